// Round 9
// baseline (273.138 us; speedup 1.0000x reference)
//
#include <hip/hip_runtime.h>

// Self-attention (B=8, N=4096, C=128) + residual + inference BatchNorm.
// R19 = R18's lean block x R12's grid, minus the poison. R18 showed LDS/VGPR
// were fine (32KB, 92 reg) but occupancy stuck at 19.5% -> the limiter is the
// GRID: 512 blocks / 256 CUs = 2 blocks/CU, period. R12 already tried grid
// 1024 and lost -- but via __launch_bounds__(256,4)'s VGPR squeeze to 64
// (confirmed poison 3x: R12/R13/R17). Also FETCH stayed ~20MB even at grid
// 1024 (L2/L3 absorb re-reads), killing the "doubled traffic" story.
// This round: QBLK=32, grid(1024), NO occupancy attributes.
//  - per-wave/tile: 8 S-MFMA + 8 exp2 + 8 PV-MFMA; working set ~80 VGPR.
//  - LDS 24KB (Kt 16KB wave-private quarters + 2x4KB Pbuf) -> 4 blocks/CU.
//  - K/V XCD-local (b = blk&7), 2MB/batch fits 4MB L2; L2 ~25 TB/s < 34.5.
//  - R14/R18 1-barrier PV-pipelined loop verbatim, q-axis halved.
//
// ws: Wt 96KB | Qg 8M | Kg(swizzled) 8M | Vtg 8M  (~25.3 MB)

typedef __attribute__((ext_vector_type(8))) short bf16x8;
typedef __attribute__((ext_vector_type(4))) float f32x4;

__device__ __forceinline__ unsigned short f2bf(float f) {
  unsigned int u = __builtin_bit_cast(unsigned int, f);
  u += 0x7fffu + ((u >> 16) & 1u);   // RNE
  return (unsigned short)(u >> 16);
}
__device__ __forceinline__ unsigned int pack2(float a, float b) {
  return (unsigned int)f2bf(a) | ((unsigned int)f2bf(b) << 16);
}
// truncating pack via v_perm_b32: D = {b.hi16, a.hi16} in 1 VALU op
__device__ __forceinline__ unsigned int pack2t(float a, float b) {
  return __builtin_amdgcn_perm(__builtin_bit_cast(unsigned int, b),
                               __builtin_bit_cast(unsigned int, a),
                               0x07060302u);
}
// raw v_exp_f32 (args bounded: |s~| <~ 15, no guards needed)
__device__ __forceinline__ float fexp2(float x) {
  return __builtin_amdgcn_exp2f(x);
}

// async global->LDS DMA, 16B/lane: lds dest = uniform base + lane*16
__device__ __forceinline__ void dma16(const void* g, void* l) {
  __builtin_amdgcn_global_load_lds(
      (const __attribute__((address_space(1))) unsigned int*)g,
      (__attribute__((address_space(3))) unsigned int*)l, 16, 0, 0);
}

// 1/sqrt(128) * log2(e): softmax in exp2 domain; folded into Wq/bq.
#define SCALE_Q (0.08838834764831845f * 1.44269504088896340f)

// ---------------------------------------------------------------------------
// Kernel 1: W[k][n] fp32 -> Wt[n][k] bf16 (Wq pre-scaled). LDS-staged,
// coalesced loads (float4 linear) and stores (uint4, 16 lanes cover a row).
// ---------------------------------------------------------------------------
__global__ __launch_bounds__(256) void prep_wt(
    const float* __restrict__ wq, const float* __restrict__ wk,
    const float* __restrict__ wv, unsigned short* __restrict__ wt) {
  __shared__ float ws[128 * 129];   // padded: read bank spread
  const float* W = (blockIdx.x == 0) ? wq : (blockIdx.x == 1 ? wk : wv);
  const float sc = (blockIdx.x == 0) ? SCALE_Q : 1.0f;
  unsigned short* out = wt + blockIdx.x * 16384;
  const int t = threadIdx.x;

#pragma unroll
  for (int i = 0; i < 16; ++i) {
    int e = (i * 256 + t) * 4;          // linear float index, coalesced
    float4 v = *(const float4*)(W + e);
    int k = e >> 7, c = e & 127;
    float* d = ws + k * 129 + c;
    d[0] = v.x; d[1] = v.y; d[2] = v.z; d[3] = v.w;
  }
  __syncthreads();

  const int c = t & 15, n0 = t >> 4;   // 16 lanes cover one 256B output row
#pragma unroll
  for (int pass = 0; pass < 8; ++pass) {
    int n = pass * 16 + n0;
    const float* col = ws + n;
    unsigned int u0 = pack2(col[(c * 8 + 0) * 129] * sc, col[(c * 8 + 1) * 129] * sc);
    unsigned int u1 = pack2(col[(c * 8 + 2) * 129] * sc, col[(c * 8 + 3) * 129] * sc);
    unsigned int u2 = pack2(col[(c * 8 + 4) * 129] * sc, col[(c * 8 + 5) * 129] * sc);
    unsigned int u3 = pack2(col[(c * 8 + 6) * 129] * sc, col[(c * 8 + 7) * 129] * sc);
    *(uint4*)(out + n * 128 + c * 8) = make_uint4(u0, u1, u2, u3);
  }
}

// ---------------------------------------------------------------------------
// Kernel 2: fused QKV projection, grid(512). One x staging, three GEMMs with
// register-resident a-frags; obuf reused per-phase (barrier-separated).
// K stored pre-swizzled (chunk ^ row) with COALESCED stores (pos-major).
// ---------------------------------------------------------------------------
__global__ __launch_bounds__(256) void qkv_proj(
    const float* __restrict__ x, const unsigned short* __restrict__ wt,
    const float* __restrict__ bq, const float* __restrict__ bk, const float* __restrict__ bv,
    unsigned short* __restrict__ Qg, unsigned short* __restrict__ Kg,
    unsigned short* __restrict__ Vtg) {
  __shared__ unsigned short xs[64 * 128];    // swizzled bf16 x tile (16 KB)
  __shared__ unsigned short obuf[9216];      // bounce buffer (18 KB), reused x3
  const int t = threadIdx.x;
  const int rowblk = blockIdx.x * 64;

#pragma unroll
  for (int i = 0; i < 8; ++i) {
    int flat = t * 4 + i * 1024;
    int row = flat >> 7, col = flat & 127;
    float4 v = *(const float4*)(x + (size_t)(rowblk + row) * 128 + col);
    unsigned int u0 = pack2(v.x, v.y), u1 = pack2(v.z, v.w);
    int pos = (col >> 3) ^ (row & 15);
    *(uint2*)(xs + row * 128 + pos * 8 + (col & 7)) = make_uint2(u0, u1);
  }
  __syncthreads();

  const int lane = t & 63, wv_ = t >> 6;
  const int lm = lane & 15, quad = lane >> 4;

  bf16x8 a[4];
  {
    int row = wv_ * 16 + lm;
#pragma unroll
    for (int ks = 0; ks < 4; ++ks)
      a[ks] = __builtin_bit_cast(bf16x8,
          *(const uint4*)(xs + row * 128 + (((ks * 4 + quad) ^ lm) * 8)));
  }

  const int b   = rowblk >> 12;
  const int nb0 = rowblk & 4095;
  const f32x4 zero4 = {0.f, 0.f, 0.f, 0.f};

#pragma unroll
  for (int p = 0; p < 3; ++p) {
    const unsigned short* w = wt + p * 16384;
    const float* bias = (p == 0) ? bq : (p == 1 ? bk : bv);
    const float bsc = (p == 0) ? SCALE_Q : 1.0f;

    f32x4 acc[8];
#pragma unroll
    for (int ct = 0; ct < 8; ++ct) acc[ct] = zero4;

#pragma unroll
    for (int ct = 0; ct < 8; ++ct) {
      int n = ct * 16 + lm;
      const uint4* wp = (const uint4*)(w + n * 128 + quad * 8);
#pragma unroll
      for (int ks = 0; ks < 4; ++ks) {
        bf16x8 bfr = __builtin_bit_cast(bf16x8, wp[ks * 4]);
        acc[ct] = __builtin_amdgcn_mfma_f32_16x16x32_bf16(a[ks], bfr, acc[ct], 0, 0, 0);
      }
    }

    if (p < 2) {
      int rowb = wv_ * 16 + quad * 4;
#pragma unroll
      for (int ct = 0; ct < 8; ++ct) {
        int c = ct * 16 + lm;
        float bb = bias[c] * bsc;
#pragma unroll
        for (int r = 0; r < 4; ++r)
          obuf[(rowb + r) * 136 + c] = f2bf(acc[ct][r] + bb);
      }
      __syncthreads();
      unsigned short* og = (p == 0) ? Qg : Kg;
      int row = t >> 2;
#pragma unroll
      for (int j = 0; j < 4; ++j) {
        int pos = (t & 3) * 4 + j;                      // contiguous store pos
        int ch  = (p == 1) ? (pos ^ (row & 15)) : pos;  // LDS-side scatter
        uint4 vv = *(const uint4*)(obuf + row * 136 + ch * 8);
        *(uint4*)(og + (size_t)(rowblk + row) * 128 + pos * 8) = vv;
      }
      __syncthreads();   // obuf free for next phase
    } else {
      int key_base = wv_ * 16 + quad * 4;
#pragma unroll
      for (int ct = 0; ct < 8; ++ct) {
        int c = ct * 16 + lm;
        float bb = bias[c];
        unsigned int u0 = pack2(acc[ct][0] + bb, acc[ct][1] + bb);
        unsigned int u1 = pack2(acc[ct][2] + bb, acc[ct][3] + bb);
        *(uint2*)(obuf + c * 72 + key_base) = make_uint2(u0, u1);
      }
      __syncthreads();
      int d = t >> 1;
#pragma unroll
      for (int j = 0; j < 4; ++j) {
        int ch = (t & 1) * 4 + j;
        uint4 vv = *(const uint4*)(obuf + d * 72 + ch * 8);
        *(uint4*)(Vtg + (size_t)b * 524288 + (size_t)d * 4096 + nb0 + ch * 8) = vv;
      }
    }
  }
}

// ---------------------------------------------------------------------------
// Kernel 3: flash attention, KVBLK=64 QBLK=32, PV pipelined one tile back,
// 1 barrier/tile. grid(1024) = 8b (XCD-local K/V) x 128 q-tiles of 32 rows;
// 256 thr = 4 waves. LDS 24KB, natural VGPR (~80) -> 4 blocks/CU.
// Per tile (64): vmcnt(4) [own K DMA] -> S (8 MFMA) -> softmax (8 exp2) ->
// lgkm, DMA K[t+1] -> PV[t-1] (8 MFMA) -> V[t] loads -> lgkm+barrier.
// ---------------------------------------------------------------------------
__global__ __launch_bounds__(256)
void flash_attn(
    const unsigned short* __restrict__ Qg, const unsigned short* __restrict__ Kg,
    const unsigned short* __restrict__ Vtg, const float* __restrict__ x,
    const float* __restrict__ gamma, const float* __restrict__ beta,
    const float* __restrict__ mmean, const float* __restrict__ mvar,
    float* __restrict__ out) {
  __shared__ unsigned short Kt[8192];        // 16 KB, wave-private 4KB quarters
  __shared__ unsigned short Pbuf[2][2048];   // 2 x 4 KB (32 q x 64 key)

  const int b  = blockIdx.x & 7;
  const int qt = blockIdx.x >> 3;          // 0..127
  const int t = threadIdx.x;
  const int lane = t & 63;
  const int w = t >> 6;                    // 0..3
  const int lm = lane & 15, quad = lane >> 4;
  const int q0 = qt * 32;

  const unsigned short* Qb = Qg  + (size_t)b * 524288;
  const unsigned short* Kb = Kg  + (size_t)b * 524288;
  const unsigned short* Vb = Vtg + (size_t)b * 524288;

  // K[0] DMA FIRST (4 reqs, oldest vmcnt entries). Wave quarter = keys w*16..+16.
  {
    const unsigned short* src = Kb + (size_t)w * 2048 + lane * 8;
    unsigned short* dst = &Kt[w * 2048];
#pragma unroll
    for (int j = 0; j < 4; ++j) dma16(src + j * 512, dst + j * 512);
  }

  // Q as B-fragments (k=d, n=q), register-resident (pre-scaled), 32 q rows
  bf16x8 qf[2][4];
#pragma unroll
  for (int nt = 0; nt < 2; ++nt) {
    const uint4* qp = (const uint4*)(Qb + (size_t)(q0 + nt * 16 + lm) * 128 + quad * 8);
#pragma unroll
    for (int ks = 0; ks < 4; ++ks) qf[nt][ks] = __builtin_bit_cast(bf16x8, qp[ks * 4]);
  }

  const f32x4 zero4 = {0.f, 0.f, 0.f, 0.f};
  f32x4 o[2][2];
#pragma unroll
  for (int mt = 0; mt < 2; ++mt)
#pragma unroll
    for (int nt = 0; nt < 2; ++nt) o[mt][nt] = zero4;
  float lp[2] = {0.f, 0.f};
  bf16x8 vf[2][2];   // V[t] regs (32d x 64 keys); consumed by PV[t] next iter

#pragma unroll 1
  for (int kt = 0; kt < 64; ++kt) {
    const int key0 = kt * 64;

    // own K[kt] DMA (4 oldest vmem entries) landed; V[kt-1] (4 newer) and the
    // qf tail at kt=0 may stay in flight.
    asm volatile("s_waitcnt vmcnt(4)" ::: "memory");

    // S^T = K * Q^T: own 16 keys (LDS, swizzled chunks) x 32 q. 8 MFMAs.
    f32x4 sa[2];
#pragma unroll
    for (int nt = 0; nt < 2; ++nt) sa[nt] = zero4;
    {
      const unsigned short* kr = &Kt[(w * 16 + lm) * 128];
      bf16x8 kf[4];
#pragma unroll
      for (int ks = 0; ks < 4; ++ks)
        kf[ks] = __builtin_bit_cast(bf16x8, *(const uint4*)(kr + ((ks * 4 + quad) ^ lm) * 8));
#pragma unroll
      for (int ks = 0; ks < 4; ++ks)
#pragma unroll
        for (int nt = 0; nt < 2; ++nt)
          sa[nt] = __builtin_amdgcn_mfma_f32_16x16x32_bf16(kf[ks], qf[nt][ks], sa[nt], 0, 0, 0);
    }

    // softmax[kt] -> Pbuf[kt&1]: keys w*16+quad*4+r, q = nt*16+lm.
    // chunk c8 = w*2+(quad>>1) of 8; row-swizzle pos = c8 ^ (q&7).
    {
      unsigned short* Ps = Pbuf[kt & 1];
      const int c8 = w * 2 + (quad >> 1);
      const int sub = (quad & 1) * 4;
#pragma unroll
      for (int nt = 0; nt < 2; ++nt) {
        float e0 = fexp2(sa[nt][0]), e1 = fexp2(sa[nt][1]);
        float e2 = fexp2(sa[nt][2]), e3 = fexp2(sa[nt][3]);
        lp[nt] += (e0 + e1) + (e2 + e3);
        int pos = c8 ^ (lm & 7);
        *(uint2*)(Ps + (nt * 16 + lm) * 64 + pos * 8 + sub) =
            make_uint2(pack2t(e0, e1), pack2t(e2, e3));
      }
    }

    // own kf reads retired -> overwrite own quarter; DMA K[kt+1] (4 reqs)
    asm volatile("s_waitcnt lgkmcnt(0)" ::: "memory");
    if (kt + 1 < 64) {
      const unsigned short* src = Kb + (size_t)(kt + 1) * 8192 + w * 2048 + lane * 8;
      unsigned short* dst = &Kt[w * 2048];
#pragma unroll
      for (int j = 0; j < 4; ++j) dma16(src + j * 512, dst + j * 512);
    }

    // PV[kt-1]: O^T += V^T[kt-1] * P^T[kt-1] (Pbuf[(kt-1)&1], vf regs).
    // vf wait is compiler-counted (4 DMA newer -> vmcnt(4)), DMA stays live.
    if (kt > 0) {
      const uint4* Pr = (const uint4*)Pbuf[(kt & 1) ^ 1];
#pragma unroll
      for (int nt = 0; nt < 2; ++nt) {
        bf16x8 pf[2];
#pragma unroll
        for (int ks = 0; ks < 2; ++ks)
          pf[ks] = __builtin_bit_cast(bf16x8, Pr[(nt * 16 + lm) * 8 + ((ks * 4 + quad) ^ (lm & 7))]);
#pragma unroll
        for (int ks = 0; ks < 2; ++ks)
#pragma unroll
          for (int mt = 0; mt < 2; ++mt)
            o[mt][nt] = __builtin_amdgcn_mfma_f32_16x16x32_bf16(vf[mt][ks], pf[ks], o[mt][nt], 0, 0, 0);
      }
    }

    // V[kt] loads -> vf (consumed next iter; window = barrier + S + softmax)
#pragma unroll
    for (int mt = 0; mt < 2; ++mt) {
      const uint4* vp = (const uint4*)(Vb + (size_t)(w * 32 + mt * 16 + lm) * 4096 + key0 + quad * 8);
#pragma unroll
      for (int ks = 0; ks < 2; ++ks) vf[mt][ks] = __builtin_bit_cast(bf16x8, vp[ks * 4]);
    }

    // single barrier: P[kt] visible; all pf reads of Pbuf[(kt-1)&1] retired
    // (lgkm only -- V loads + K DMA stay in flight)
    asm volatile("s_waitcnt lgkmcnt(0)\n\ts_barrier" ::: "memory");
  }

  // epilogue: PV[63] (Pbuf[1], vf = V[63]; compiler waits the V loads)
  {
    const uint4* Pr = (const uint4*)Pbuf[1];
#pragma unroll
    for (int nt = 0; nt < 2; ++nt) {
      bf16x8 pf[2];
#pragma unroll
      for (int ks = 0; ks < 2; ++ks)
        pf[ks] = __builtin_bit_cast(bf16x8, Pr[(nt * 16 + lm) * 8 + ((ks * 4 + quad) ^ (lm & 7))]);
#pragma unroll
      for (int ks = 0; ks < 2; ++ks)
#pragma unroll
        for (int mt = 0; mt < 2; ++mt)
          o[mt][nt] = __builtin_amdgcn_mfma_f32_16x16x32_bf16(vf[mt][ks], pf[ks], o[mt][nt], 0, 0, 0);
    }
  }

  // l reduction: quads (keys) in-wave via shfl, then across waves via Pbuf[0]
  // floats (disjoint from Pbuf[1] still read by other waves' epilogue PV)
  float* lred = (float*)Pbuf[0];
#pragma unroll
  for (int nt = 0; nt < 2; ++nt) {
    lp[nt] += __shfl_xor(lp[nt], 16);
    lp[nt] += __shfl_xor(lp[nt], 32);
  }
  if (quad == 0) {
#pragma unroll
    for (int nt = 0; nt < 2; ++nt) lred[w * 32 + nt * 16 + lm] = lp[nt];
  }
  __syncthreads();
  float rl[2];
#pragma unroll
  for (int nt = 0; nt < 2; ++nt) {
    int q = nt * 16 + lm;
    rl[nt] = 1.0f / ((lred[q] + lred[32 + q]) + (lred[64 + q] + lred[96 + q]));
  }

  // epilogue: lane holds 4 consecutive d at fixed q -> float4 stores
#pragma unroll
  for (int mt = 0; mt < 2; ++mt) {
    int c0 = w * 32 + mt * 16 + quad * 4;
    float4 gm = *(const float4*)(gamma + c0);
    float4 bt = *(const float4*)(beta + c0);
    float4 mm = *(const float4*)(mmean + c0);
    float4 mv = *(const float4*)(mvar + c0);
    float iv0 = gm.x * rsqrtf(mv.x + 1e-3f), iv1 = gm.y * rsqrtf(mv.y + 1e-3f);
    float iv2 = gm.z * rsqrtf(mv.z + 1e-3f), iv3 = gm.w * rsqrtf(mv.w + 1e-3f);
    float ad0 = bt.x - mm.x * iv0, ad1 = bt.y - mm.y * iv1;
    float ad2 = bt.z - mm.z * iv2, ad3 = bt.w - mm.w * iv3;
#pragma unroll
    for (int nt = 0; nt < 2; ++nt) {
      size_t g = ((size_t)b * 4096 + q0 + nt * 16 + lm) * 128 + c0;
      float4 xr = *(const float4*)(x + g);
      float4 ov;
      ov.x = (o[mt][nt][0] * rl[nt] + xr.x) * iv0 + ad0;
      ov.y = (o[mt][nt][1] * rl[nt] + xr.y) * iv1 + ad1;
      ov.z = (o[mt][nt][2] * rl[nt] + xr.z) * iv2 + ad2;
      ov.w = (o[mt][nt][3] * rl[nt] + xr.w) * iv3 + ad3;
      *(float4*)(out + g) = ov;
    }
  }
}

// ---------------------------------------------------------------------------
extern "C" void kernel_launch(void* const* d_in, const int* in_sizes, int n_in,
                              void* d_out, int out_size, void* d_ws, size_t ws_size,
                              hipStream_t stream) {
  const float* x     = (const float*)d_in[0];
  const float* wq    = (const float*)d_in[1];
  const float* bq    = (const float*)d_in[2];
  const float* wk    = (const float*)d_in[3];
  const float* bk    = (const float*)d_in[4];
  const float* wv    = (const float*)d_in[5];
  const float* bv    = (const float*)d_in[6];
  const float* gamma = (const float*)d_in[7];
  const float* beta  = (const float*)d_in[8];
  const float* mmean = (const float*)d_in[9];
  const float* mvar  = (const float*)d_in[10];
  float* out = (float*)d_out;

  unsigned short* wt  = (unsigned short*)d_ws;
  unsigned short* Qg  = wt + 3 * 128 * 128;
  unsigned short* Kg  = Qg + 8 * 4096 * 128;     // pre-swizzled rows
  unsigned short* Vtg = Kg + 8 * 4096 * 128;

  prep_wt<<<dim3(3), dim3(256), 0, stream>>>(wq, wk, wv, wt);
  qkv_proj<<<dim3(512), dim3(256), 0, stream>>>(x, wt, bq, bk, bv, Qg, Kg, Vtg);
  flash_attn<<<dim3(1024), dim3(256), 0, stream>>>(Qg, Kg, Vtg, x, gamma, beta,
                                                   mmean, mvar, out);
}

// Round 10
// 218.721 us; speedup vs baseline: 1.2488x; 1.2488x over previous
//
#include <hip/hip_runtime.h>

// Self-attention (B=8, N=4096, C=128) + residual + inference BatchNorm.
// R20: fat waves x high TLP -- the untested quadrant. Evidence table:
// VGPR>=92 (fat Q/V prefetch) always ~103us; VGPR<=64 always ~170us,
// regardless of occupancy (R12/13/17/19). This round keeps the R15 champion's
// per-block shape (QBLK=64, KVBLK=128, LDS 64KB, grid 512) but splits it over
// 8 waves (512 thr): wave w owns keys w*16..+16 for S and d w*16..+16 for PV.
// qf stays [4][4] (64 VGPR, all 64 q), V-prefetch depth unchanged -> natural
// VGPR ~120; 4x120 <= 512 -> up to 4 waves/SIMD at 2 blocks/CU.
// R14's 1-barrier PV-pipelined loop verbatim (counts halved: 4-req K-DMA,
// vmcnt(4), 16 S + 16 PV MFMA/wave/tile). Wave-private K quarters preserved
// (wave reads only its own 16 rows) -> no barrier for K, lgkm-only barriers.
//
// ws: Wt 96KB | Qg 8M | Kg(swizzled) 8M | Vtg 8M  (~25.3 MB)

typedef __attribute__((ext_vector_type(8))) short bf16x8;
typedef __attribute__((ext_vector_type(4))) float f32x4;

__device__ __forceinline__ unsigned short f2bf(float f) {
  unsigned int u = __builtin_bit_cast(unsigned int, f);
  u += 0x7fffu + ((u >> 16) & 1u);   // RNE
  return (unsigned short)(u >> 16);
}
__device__ __forceinline__ unsigned int pack2(float a, float b) {
  return (unsigned int)f2bf(a) | ((unsigned int)f2bf(b) << 16);
}
// truncating pack via v_perm_b32: D = {b.hi16, a.hi16} in 1 VALU op
__device__ __forceinline__ unsigned int pack2t(float a, float b) {
  return __builtin_amdgcn_perm(__builtin_bit_cast(unsigned int, b),
                               __builtin_bit_cast(unsigned int, a),
                               0x07060302u);
}
// raw v_exp_f32 (args bounded: |s~| <~ 15, no guards needed)
__device__ __forceinline__ float fexp2(float x) {
  return __builtin_amdgcn_exp2f(x);
}

// async global->LDS DMA, 16B/lane: lds dest = uniform base + lane*16
__device__ __forceinline__ void dma16(const void* g, void* l) {
  __builtin_amdgcn_global_load_lds(
      (const __attribute__((address_space(1))) unsigned int*)g,
      (__attribute__((address_space(3))) unsigned int*)l, 16, 0, 0);
}

// 1/sqrt(128) * log2(e): softmax in exp2 domain; folded into Wq/bq.
#define SCALE_Q (0.08838834764831845f * 1.44269504088896340f)

// ---------------------------------------------------------------------------
// Kernel 1: W[k][n] fp32 -> Wt[n][k] bf16 (Wq pre-scaled). LDS-staged,
// coalesced loads (float4 linear) and stores (uint4, 16 lanes cover a row).
// ---------------------------------------------------------------------------
__global__ __launch_bounds__(256) void prep_wt(
    const float* __restrict__ wq, const float* __restrict__ wk,
    const float* __restrict__ wv, unsigned short* __restrict__ wt) {
  __shared__ float ws[128 * 129];   // padded: read bank spread
  const float* W = (blockIdx.x == 0) ? wq : (blockIdx.x == 1 ? wk : wv);
  const float sc = (blockIdx.x == 0) ? SCALE_Q : 1.0f;
  unsigned short* out = wt + blockIdx.x * 16384;
  const int t = threadIdx.x;

#pragma unroll
  for (int i = 0; i < 16; ++i) {
    int e = (i * 256 + t) * 4;          // linear float index, coalesced
    float4 v = *(const float4*)(W + e);
    int k = e >> 7, c = e & 127;
    float* d = ws + k * 129 + c;
    d[0] = v.x; d[1] = v.y; d[2] = v.z; d[3] = v.w;
  }
  __syncthreads();

  const int c = t & 15, n0 = t >> 4;   // 16 lanes cover one 256B output row
#pragma unroll
  for (int pass = 0; pass < 8; ++pass) {
    int n = pass * 16 + n0;
    const float* col = ws + n;
    unsigned int u0 = pack2(col[(c * 8 + 0) * 129] * sc, col[(c * 8 + 1) * 129] * sc);
    unsigned int u1 = pack2(col[(c * 8 + 2) * 129] * sc, col[(c * 8 + 3) * 129] * sc);
    unsigned int u2 = pack2(col[(c * 8 + 4) * 129] * sc, col[(c * 8 + 5) * 129] * sc);
    unsigned int u3 = pack2(col[(c * 8 + 6) * 129] * sc, col[(c * 8 + 7) * 129] * sc);
    *(uint4*)(out + n * 128 + c * 8) = make_uint4(u0, u1, u2, u3);
  }
}

// ---------------------------------------------------------------------------
// Kernel 2: fused QKV projection, grid(512). One x staging, three GEMMs with
// register-resident a-frags; obuf reused per-phase (barrier-separated).
// K stored pre-swizzled (chunk ^ row) with COALESCED stores (pos-major).
// ---------------------------------------------------------------------------
__global__ __launch_bounds__(256) void qkv_proj(
    const float* __restrict__ x, const unsigned short* __restrict__ wt,
    const float* __restrict__ bq, const float* __restrict__ bk, const float* __restrict__ bv,
    unsigned short* __restrict__ Qg, unsigned short* __restrict__ Kg,
    unsigned short* __restrict__ Vtg) {
  __shared__ unsigned short xs[64 * 128];    // swizzled bf16 x tile (16 KB)
  __shared__ unsigned short obuf[9216];      // bounce buffer (18 KB), reused x3
  const int t = threadIdx.x;
  const int rowblk = blockIdx.x * 64;

#pragma unroll
  for (int i = 0; i < 8; ++i) {
    int flat = t * 4 + i * 1024;
    int row = flat >> 7, col = flat & 127;
    float4 v = *(const float4*)(x + (size_t)(rowblk + row) * 128 + col);
    unsigned int u0 = pack2(v.x, v.y), u1 = pack2(v.z, v.w);
    int pos = (col >> 3) ^ (row & 15);
    *(uint2*)(xs + row * 128 + pos * 8 + (col & 7)) = make_uint2(u0, u1);
  }
  __syncthreads();

  const int lane = t & 63, wv_ = t >> 6;
  const int lm = lane & 15, quad = lane >> 4;

  bf16x8 a[4];
  {
    int row = wv_ * 16 + lm;
#pragma unroll
    for (int ks = 0; ks < 4; ++ks)
      a[ks] = __builtin_bit_cast(bf16x8,
          *(const uint4*)(xs + row * 128 + (((ks * 4 + quad) ^ lm) * 8)));
  }

  const int b   = rowblk >> 12;
  const int nb0 = rowblk & 4095;
  const f32x4 zero4 = {0.f, 0.f, 0.f, 0.f};

#pragma unroll
  for (int p = 0; p < 3; ++p) {
    const unsigned short* w = wt + p * 16384;
    const float* bias = (p == 0) ? bq : (p == 1 ? bk : bv);
    const float bsc = (p == 0) ? SCALE_Q : 1.0f;

    f32x4 acc[8];
#pragma unroll
    for (int ct = 0; ct < 8; ++ct) acc[ct] = zero4;

#pragma unroll
    for (int ct = 0; ct < 8; ++ct) {
      int n = ct * 16 + lm;
      const uint4* wp = (const uint4*)(w + n * 128 + quad * 8);
#pragma unroll
      for (int ks = 0; ks < 4; ++ks) {
        bf16x8 bfr = __builtin_bit_cast(bf16x8, wp[ks * 4]);
        acc[ct] = __builtin_amdgcn_mfma_f32_16x16x32_bf16(a[ks], bfr, acc[ct], 0, 0, 0);
      }
    }

    if (p < 2) {
      int rowb = wv_ * 16 + quad * 4;
#pragma unroll
      for (int ct = 0; ct < 8; ++ct) {
        int c = ct * 16 + lm;
        float bb = bias[c] * bsc;
#pragma unroll
        for (int r = 0; r < 4; ++r)
          obuf[(rowb + r) * 136 + c] = f2bf(acc[ct][r] + bb);
      }
      __syncthreads();
      unsigned short* og = (p == 0) ? Qg : Kg;
      int row = t >> 2;
#pragma unroll
      for (int j = 0; j < 4; ++j) {
        int pos = (t & 3) * 4 + j;                      // contiguous store pos
        int ch  = (p == 1) ? (pos ^ (row & 15)) : pos;  // LDS-side scatter
        uint4 vv = *(const uint4*)(obuf + row * 136 + ch * 8);
        *(uint4*)(og + (size_t)(rowblk + row) * 128 + pos * 8) = vv;
      }
      __syncthreads();   // obuf free for next phase
    } else {
      int key_base = wv_ * 16 + quad * 4;
#pragma unroll
      for (int ct = 0; ct < 8; ++ct) {
        int c = ct * 16 + lm;
        float bb = bias[c];
        unsigned int u0 = pack2(acc[ct][0] + bb, acc[ct][1] + bb);
        unsigned int u1 = pack2(acc[ct][2] + bb, acc[ct][3] + bb);
        *(uint2*)(obuf + c * 72 + key_base) = make_uint2(u0, u1);
      }
      __syncthreads();
      int d = t >> 1;
#pragma unroll
      for (int j = 0; j < 4; ++j) {
        int ch = (t & 1) * 4 + j;
        uint4 vv = *(const uint4*)(obuf + d * 72 + ch * 8);
        *(uint4*)(Vtg + (size_t)b * 524288 + (size_t)d * 4096 + nb0 + ch * 8) = vv;
      }
    }
  }
}

// ---------------------------------------------------------------------------
// Kernel 3: flash attention, 8 waves (512 thr), QBLK=64, KVBLK=128.
// Wave w: S for keys w*16..+16 x all 64 q (16 MFMA); PV for d w*16..+16 x all
// 64 q over all 128 keys (16 MFMA). qf[4][4] register-resident (fat wave).
// PV pipelined one tile back; 1 lgkm-only barrier/tile (P exchange only);
// K quarters wave-private (no K barrier). LDS 64KB -> 2 blocks/CU; natural
// VGPR (~120) -> 3-4 waves/SIMD. grid(512) = 8b (XCD-local K/V) x 64 q-tiles.
// ---------------------------------------------------------------------------
__global__ __launch_bounds__(512)
void flash_attn(
    const unsigned short* __restrict__ Qg, const unsigned short* __restrict__ Kg,
    const unsigned short* __restrict__ Vtg, const float* __restrict__ x,
    const float* __restrict__ gamma, const float* __restrict__ beta,
    const float* __restrict__ mmean, const float* __restrict__ mvar,
    float* __restrict__ out) {
  __shared__ unsigned short Kt[16384];       // 32 KB, wave-private 4KB eighths
  __shared__ unsigned short Pbuf[2][8192];   // 2 x 16 KB (64 q x 128 key)

  const int b  = blockIdx.x & 7;
  const int qt = blockIdx.x >> 3;          // 0..63
  const int t = threadIdx.x;
  const int lane = t & 63;
  const int w = t >> 6;                    // 0..7
  const int lm = lane & 15, quad = lane >> 4;
  const int q0 = qt * 64;

  const unsigned short* Qb = Qg  + (size_t)b * 524288;
  const unsigned short* Kb = Kg  + (size_t)b * 524288;
  const unsigned short* Vb = Vtg + (size_t)b * 524288;

  // K[0] DMA FIRST (4 reqs, oldest vmcnt entries). Wave eighth = keys w*16..+16.
  {
    const unsigned short* src = Kb + (size_t)w * 2048 + lane * 8;
    unsigned short* dst = &Kt[w * 2048];
#pragma unroll
    for (int j = 0; j < 4; ++j) dma16(src + j * 512, dst + j * 512);
  }

  // Q as B-fragments (k=d, n=q), register-resident (pre-scaled), all 64 q
  bf16x8 qf[4][4];
#pragma unroll
  for (int nt = 0; nt < 4; ++nt) {
    const uint4* qp = (const uint4*)(Qb + (size_t)(q0 + nt * 16 + lm) * 128 + quad * 8);
#pragma unroll
    for (int ks = 0; ks < 4; ++ks) qf[nt][ks] = __builtin_bit_cast(bf16x8, qp[ks * 4]);
  }

  const f32x4 zero4 = {0.f, 0.f, 0.f, 0.f};
  f32x4 o[4];                // O^T: own 16 d x 64 q
#pragma unroll
  for (int nt = 0; nt < 4; ++nt) o[nt] = zero4;
  float lp[4] = {0.f, 0.f, 0.f, 0.f};
  bf16x8 vf[4];              // V[t] regs (own 16 d x 128 keys); used by PV[t] next iter

#pragma unroll 1
  for (int kt = 0; kt < 32; ++kt) {
    const int key0 = kt * 128;

    // own K[kt] DMA = the 4 oldest vmem entries (V[kt-1] issued after it);
    // at kt=0 this also drains 12 of the qf loads (needed by S anyway).
    asm volatile("s_waitcnt vmcnt(4)" ::: "memory");

    // S^T = K * Q^T: own 16 keys (LDS, swizzled chunks) x 64 q. 16 MFMAs.
    f32x4 sa[4];
#pragma unroll
    for (int nt = 0; nt < 4; ++nt) sa[nt] = zero4;
    {
      const unsigned short* kr = &Kt[(w * 16 + lm) * 128];
      bf16x8 kf[4];
#pragma unroll
      for (int ks = 0; ks < 4; ++ks)
        kf[ks] = __builtin_bit_cast(bf16x8, *(const uint4*)(kr + ((ks * 4 + quad) ^ lm) * 8));
#pragma unroll
      for (int ks = 0; ks < 4; ++ks)
#pragma unroll
        for (int nt = 0; nt < 4; ++nt)
          sa[nt] = __builtin_amdgcn_mfma_f32_16x16x32_bf16(kf[ks], qf[nt][ks], sa[nt], 0, 0, 0);
    }

    // softmax[kt] -> Pbuf[kt&1]: own keys = chunks w*2, w*2+1 of 16.
    // key = w*16 + quad*4 + reg; chunk c16 = w*2 + (quad>>1), sub = (quad&1)*4.
    {
      unsigned short* Ps = Pbuf[kt & 1];
      const int c16 = w * 2 + (quad >> 1);
      const int sub = (quad & 1) * 4;
#pragma unroll
      for (int nt = 0; nt < 4; ++nt) {
        float e0 = fexp2(sa[nt][0]), e1 = fexp2(sa[nt][1]);
        float e2 = fexp2(sa[nt][2]), e3 = fexp2(sa[nt][3]);
        lp[nt] += (e0 + e1) + (e2 + e3);
        int pos = c16 ^ lm;
        *(uint2*)(Ps + (nt * 16 + lm) * 128 + pos * 8 + sub) =
            make_uint2(pack2t(e0, e1), pack2t(e2, e3));
      }
    }

    // own kf reads retired -> safe to overwrite own eighth; DMA K[kt+1]
    asm volatile("s_waitcnt lgkmcnt(0)" ::: "memory");
    if (kt + 1 < 32) {
      const unsigned short* src = Kb + (size_t)(kt + 1) * 16384 + w * 2048 + lane * 8;
      unsigned short* dst = &Kt[w * 2048];
#pragma unroll
      for (int j = 0; j < 4; ++j) dma16(src + j * 512, dst + j * 512);
    }

    // PV[kt-1]: O^T += V^T[kt-1] * P^T[kt-1] (Pbuf[(kt-1)&1], vf regs).
    // vf wait is compiler-counted (4 DMA newer -> vmcnt(4)), DMA stays live.
    if (kt > 0) {
      const uint4* Pr = (const uint4*)Pbuf[(kt & 1) ^ 1];
#pragma unroll
      for (int nt = 0; nt < 4; ++nt) {
        bf16x8 pf[4];
#pragma unroll
        for (int ks = 0; ks < 4; ++ks)
          pf[ks] = __builtin_bit_cast(bf16x8, Pr[(nt * 16 + lm) * 16 + ((ks * 4 + quad) ^ lm)]);
#pragma unroll
        for (int ks = 0; ks < 4; ++ks)
          o[nt] = __builtin_amdgcn_mfma_f32_16x16x32_bf16(vf[ks], pf[ks], o[nt], 0, 0, 0);
      }
    }

    // V[kt] loads -> vf (own 16 d-rows x 128 keys; consumed next iteration)
    {
      const uint4* vp = (const uint4*)(Vb + (size_t)(w * 16 + lm) * 4096 + key0 + quad * 8);
#pragma unroll
      for (int ks = 0; ks < 4; ++ks) vf[ks] = __builtin_bit_cast(bf16x8, vp[ks * 4]);
    }

    // single barrier: P[kt] visible; all pf reads of Pbuf[(kt-1)&1] retired
    // (lgkm only -- V loads + K DMA stay in flight)
    asm volatile("s_waitcnt lgkmcnt(0)\n\ts_barrier" ::: "memory");
  }

  // epilogue: PV[31] (Pbuf[1], vf = V[31]; compiler waits the V loads)
  {
    const uint4* Pr = (const uint4*)Pbuf[1];
#pragma unroll
    for (int nt = 0; nt < 4; ++nt) {
      bf16x8 pf[4];
#pragma unroll
      for (int ks = 0; ks < 4; ++ks)
        pf[ks] = __builtin_bit_cast(bf16x8, Pr[(nt * 16 + lm) * 16 + ((ks * 4 + quad) ^ lm)]);
#pragma unroll
      for (int ks = 0; ks < 4; ++ks)
        o[nt] = __builtin_amdgcn_mfma_f32_16x16x32_bf16(vf[ks], pf[ks], o[nt], 0, 0, 0);
    }
  }

  // l reduction: quads (keys) in-wave via shfl, then across 8 waves via
  // Pbuf[0] floats (disjoint from Pbuf[1] still read by epilogue PV)
  float* lred = (float*)Pbuf[0];
#pragma unroll
  for (int nt = 0; nt < 4; ++nt) {
    lp[nt] += __shfl_xor(lp[nt], 16);
    lp[nt] += __shfl_xor(lp[nt], 32);
  }
  if (quad == 0) {
#pragma unroll
    for (int nt = 0; nt < 4; ++nt) lred[w * 64 + nt * 16 + lm] = lp[nt];
  }
  __syncthreads();
  float rl[4];
#pragma unroll
  for (int nt = 0; nt < 4; ++nt) {
    int q = nt * 16 + lm;
    float s0 = (lred[q] + lred[64 + q]) + (lred[128 + q] + lred[192 + q]);
    float s1 = (lred[256 + q] + lred[320 + q]) + (lred[384 + q] + lred[448 + q]);
    rl[nt] = 1.0f / (s0 + s1);
  }

  // epilogue: lane holds 4 consecutive d at fixed q -> float4 stores
  {
    int c0 = w * 16 + quad * 4;
    float4 gm = *(const float4*)(gamma + c0);
    float4 bt = *(const float4*)(beta + c0);
    float4 mm = *(const float4*)(mmean + c0);
    float4 mv = *(const float4*)(mvar + c0);
    float iv0 = gm.x * rsqrtf(mv.x + 1e-3f), iv1 = gm.y * rsqrtf(mv.y + 1e-3f);
    float iv2 = gm.z * rsqrtf(mv.z + 1e-3f), iv3 = gm.w * rsqrtf(mv.w + 1e-3f);
    float ad0 = bt.x - mm.x * iv0, ad1 = bt.y - mm.y * iv1;
    float ad2 = bt.z - mm.z * iv2, ad3 = bt.w - mm.w * iv3;
#pragma unroll
    for (int nt = 0; nt < 4; ++nt) {
      size_t g = ((size_t)b * 4096 + q0 + nt * 16 + lm) * 128 + c0;
      float4 xr = *(const float4*)(x + g);
      float4 ov;
      ov.x = (o[nt][0] * rl[nt] + xr.x) * iv0 + ad0;
      ov.y = (o[nt][1] * rl[nt] + xr.y) * iv1 + ad1;
      ov.z = (o[nt][2] * rl[nt] + xr.z) * iv2 + ad2;
      ov.w = (o[nt][3] * rl[nt] + xr.w) * iv3 + ad3;
      *(float4*)(out + g) = ov;
    }
  }
}

// ---------------------------------------------------------------------------
extern "C" void kernel_launch(void* const* d_in, const int* in_sizes, int n_in,
                              void* d_out, int out_size, void* d_ws, size_t ws_size,
                              hipStream_t stream) {
  const float* x     = (const float*)d_in[0];
  const float* wq    = (const float*)d_in[1];
  const float* bq    = (const float*)d_in[2];
  const float* wk    = (const float*)d_in[3];
  const float* bk    = (const float*)d_in[4];
  const float* wv    = (const float*)d_in[5];
  const float* bv    = (const float*)d_in[6];
  const float* gamma = (const float*)d_in[7];
  const float* beta  = (const float*)d_in[8];
  const float* mmean = (const float*)d_in[9];
  const float* mvar  = (const float*)d_in[10];
  float* out = (float*)d_out;

  unsigned short* wt  = (unsigned short*)d_ws;
  unsigned short* Qg  = wt + 3 * 128 * 128;
  unsigned short* Kg  = Qg + 8 * 4096 * 128;     // pre-swizzled rows
  unsigned short* Vtg = Kg + 8 * 4096 * 128;

  prep_wt<<<dim3(3), dim3(256), 0, stream>>>(wq, wk, wv, wt);
  qkv_proj<<<dim3(512), dim3(256), 0, stream>>>(x, wt, bq, bk, bv, Qg, Kg, Vtg);
  flash_attn<<<dim3(512), dim3(512), 0, stream>>>(Qg, Kg, Vtg, x, gamma, beta,
                                                  mmean, mvar, out);
}

// Round 11
// 212.146 us; speedup vs baseline: 1.2875x; 1.0310x over previous
//
#include <hip/hip_runtime.h>

// Self-attention (B=8, N=4096, C=128) + residual + inference BatchNorm.
// R21: 32x32x16 MFMA port of the R15 champion (102.7us). One variable: all
// MFMAs 16x16x32 -> 32x32x16 (same FLOPs, half the instructions, m119 rate
// 2495 vs ~2176 TF; issue cycles -17%). Structure verbatim R15: QBLK=64,
// KVBLK=128, 4 waves, K DMA wave-private quarters, PV pipelined 1 tile back,
// single lgkm barrier/tile, double Pbuf. R20 closed the TLP program: every
// occupancy route fails (VGPR squeeze / thin waves / traffic+sync dup);
// per-wave efficiency is the remaining lever.
// Layouts (verified m74/m101 mapping): C/D col=lane&31, row=(reg&3)+8*(reg>>2)
// +4*(lane>>5); A/B k = (lane>>5)*8+[0..7]. kf/qf/vf/pf: chunk=ks*2+hi with
// the existing chunk^(row&15) XOR swizzle; P-write chunk = (w*4+g)^(q&15).
//
// ws: Wt 96KB | Qg 8M | Kg(swizzled) 8M | Vtg 8M  (~25.3 MB)

typedef __attribute__((ext_vector_type(8))) short bf16x8;
typedef __attribute__((ext_vector_type(4))) float f32x4;
typedef __attribute__((ext_vector_type(16))) float f32x16;

__device__ __forceinline__ unsigned short f2bf(float f) {
  unsigned int u = __builtin_bit_cast(unsigned int, f);
  u += 0x7fffu + ((u >> 16) & 1u);   // RNE
  return (unsigned short)(u >> 16);
}
__device__ __forceinline__ unsigned int pack2(float a, float b) {
  return (unsigned int)f2bf(a) | ((unsigned int)f2bf(b) << 16);
}
// truncating pack via v_perm_b32: D = {b.hi16, a.hi16} in 1 VALU op
__device__ __forceinline__ unsigned int pack2t(float a, float b) {
  return __builtin_amdgcn_perm(__builtin_bit_cast(unsigned int, b),
                               __builtin_bit_cast(unsigned int, a),
                               0x07060302u);
}
// raw v_exp_f32 (args bounded: |s~| <~ 15, no guards needed)
__device__ __forceinline__ float fexp2(float x) {
  return __builtin_amdgcn_exp2f(x);
}

// async global->LDS DMA, 16B/lane: lds dest = uniform base + lane*16
__device__ __forceinline__ void dma16(const void* g, void* l) {
  __builtin_amdgcn_global_load_lds(
      (const __attribute__((address_space(1))) unsigned int*)g,
      (__attribute__((address_space(3))) unsigned int*)l, 16, 0, 0);
}

// 1/sqrt(128) * log2(e): softmax in exp2 domain; folded into Wq/bq.
#define SCALE_Q (0.08838834764831845f * 1.44269504088896340f)

// ---------------------------------------------------------------------------
// Kernel 1: W[k][n] fp32 -> Wt[n][k] bf16 (Wq pre-scaled). LDS-staged,
// coalesced loads (float4 linear) and stores (uint4, 16 lanes cover a row).
// ---------------------------------------------------------------------------
__global__ __launch_bounds__(256) void prep_wt(
    const float* __restrict__ wq, const float* __restrict__ wk,
    const float* __restrict__ wv, unsigned short* __restrict__ wt) {
  __shared__ float ws[128 * 129];   // padded: read bank spread
  const float* W = (blockIdx.x == 0) ? wq : (blockIdx.x == 1 ? wk : wv);
  const float sc = (blockIdx.x == 0) ? SCALE_Q : 1.0f;
  unsigned short* out = wt + blockIdx.x * 16384;
  const int t = threadIdx.x;

#pragma unroll
  for (int i = 0; i < 16; ++i) {
    int e = (i * 256 + t) * 4;          // linear float index, coalesced
    float4 v = *(const float4*)(W + e);
    int k = e >> 7, c = e & 127;
    float* d = ws + k * 129 + c;
    d[0] = v.x; d[1] = v.y; d[2] = v.z; d[3] = v.w;
  }
  __syncthreads();

  const int c = t & 15, n0 = t >> 4;   // 16 lanes cover one 256B output row
#pragma unroll
  for (int pass = 0; pass < 8; ++pass) {
    int n = pass * 16 + n0;
    const float* col = ws + n;
    unsigned int u0 = pack2(col[(c * 8 + 0) * 129] * sc, col[(c * 8 + 1) * 129] * sc);
    unsigned int u1 = pack2(col[(c * 8 + 2) * 129] * sc, col[(c * 8 + 3) * 129] * sc);
    unsigned int u2 = pack2(col[(c * 8 + 4) * 129] * sc, col[(c * 8 + 5) * 129] * sc);
    unsigned int u3 = pack2(col[(c * 8 + 6) * 129] * sc, col[(c * 8 + 7) * 129] * sc);
    *(uint4*)(out + n * 128 + c * 8) = make_uint4(u0, u1, u2, u3);
  }
}

// ---------------------------------------------------------------------------
// Kernel 2: fused QKV projection, grid(512). One x staging, three GEMMs with
// register-resident a-frags; obuf reused per-phase (barrier-separated).
// K stored pre-swizzled (chunk ^ row) with COALESCED stores (pos-major).
// ---------------------------------------------------------------------------
__global__ __launch_bounds__(256) void qkv_proj(
    const float* __restrict__ x, const unsigned short* __restrict__ wt,
    const float* __restrict__ bq, const float* __restrict__ bk, const float* __restrict__ bv,
    unsigned short* __restrict__ Qg, unsigned short* __restrict__ Kg,
    unsigned short* __restrict__ Vtg) {
  __shared__ unsigned short xs[64 * 128];    // swizzled bf16 x tile (16 KB)
  __shared__ unsigned short obuf[9216];      // bounce buffer (18 KB), reused x3
  const int t = threadIdx.x;
  const int rowblk = blockIdx.x * 64;

#pragma unroll
  for (int i = 0; i < 8; ++i) {
    int flat = t * 4 + i * 1024;
    int row = flat >> 7, col = flat & 127;
    float4 v = *(const float4*)(x + (size_t)(rowblk + row) * 128 + col);
    unsigned int u0 = pack2(v.x, v.y), u1 = pack2(v.z, v.w);
    int pos = (col >> 3) ^ (row & 15);
    *(uint2*)(xs + row * 128 + pos * 8 + (col & 7)) = make_uint2(u0, u1);
  }
  __syncthreads();

  const int lane = t & 63, wv_ = t >> 6;
  const int lm = lane & 15, quad = lane >> 4;

  bf16x8 a[4];
  {
    int row = wv_ * 16 + lm;
#pragma unroll
    for (int ks = 0; ks < 4; ++ks)
      a[ks] = __builtin_bit_cast(bf16x8,
          *(const uint4*)(xs + row * 128 + (((ks * 4 + quad) ^ lm) * 8)));
  }

  const int b   = rowblk >> 12;
  const int nb0 = rowblk & 4095;
  const f32x4 zero4 = {0.f, 0.f, 0.f, 0.f};

#pragma unroll
  for (int p = 0; p < 3; ++p) {
    const unsigned short* w = wt + p * 16384;
    const float* bias = (p == 0) ? bq : (p == 1 ? bk : bv);
    const float bsc = (p == 0) ? SCALE_Q : 1.0f;

    f32x4 acc[8];
#pragma unroll
    for (int ct = 0; ct < 8; ++ct) acc[ct] = zero4;

#pragma unroll
    for (int ct = 0; ct < 8; ++ct) {
      int n = ct * 16 + lm;
      const uint4* wp = (const uint4*)(w + n * 128 + quad * 8);
#pragma unroll
      for (int ks = 0; ks < 4; ++ks) {
        bf16x8 bfr = __builtin_bit_cast(bf16x8, wp[ks * 4]);
        acc[ct] = __builtin_amdgcn_mfma_f32_16x16x32_bf16(a[ks], bfr, acc[ct], 0, 0, 0);
      }
    }

    if (p < 2) {
      int rowb = wv_ * 16 + quad * 4;
#pragma unroll
      for (int ct = 0; ct < 8; ++ct) {
        int c = ct * 16 + lm;
        float bb = bias[c] * bsc;
#pragma unroll
        for (int r = 0; r < 4; ++r)
          obuf[(rowb + r) * 136 + c] = f2bf(acc[ct][r] + bb);
      }
      __syncthreads();
      unsigned short* og = (p == 0) ? Qg : Kg;
      int row = t >> 2;
#pragma unroll
      for (int j = 0; j < 4; ++j) {
        int pos = (t & 3) * 4 + j;                      // contiguous store pos
        int ch  = (p == 1) ? (pos ^ (row & 15)) : pos;  // LDS-side scatter
        uint4 vv = *(const uint4*)(obuf + row * 136 + ch * 8);
        *(uint4*)(og + (size_t)(rowblk + row) * 128 + pos * 8) = vv;
      }
      __syncthreads();   // obuf free for next phase
    } else {
      int key_base = wv_ * 16 + quad * 4;
#pragma unroll
      for (int ct = 0; ct < 8; ++ct) {
        int c = ct * 16 + lm;
        float bb = bias[c];
        unsigned int u0 = pack2(acc[ct][0] + bb, acc[ct][1] + bb);
        unsigned int u1 = pack2(acc[ct][2] + bb, acc[ct][3] + bb);
        *(uint2*)(obuf + c * 72 + key_base) = make_uint2(u0, u1);
      }
      __syncthreads();
      int d = t >> 1;
#pragma unroll
      for (int j = 0; j < 4; ++j) {
        int ch = (t & 1) * 4 + j;
        uint4 vv = *(const uint4*)(obuf + d * 72 + ch * 8);
        *(uint4*)(Vtg + (size_t)b * 524288 + (size_t)d * 4096 + nb0 + ch * 8) = vv;
      }
    }
  }
}

// ---------------------------------------------------------------------------
// Kernel 3: flash attention, 32x32x16 MFMA. grid(512) = 8b x 64 q-tiles of 64
// rows; 256 thr = 4 waves. Wave w owns keys w*32..+32 (S, A-operand from
// wave-private LDS quarter) and d w*32..+32 (PV). PV pipelined 1 tile back,
// single lgkm barrier/tile, double Pbuf — verbatim R15 scheduling.
// Per tile/wave: 16 S-MFMA + 32 exp2 + 16 PV-MFMA (was 32+32+32 instrs).
// ---------------------------------------------------------------------------
__global__ __launch_bounds__(256)
__attribute__((amdgpu_waves_per_eu(2, 2)))
void flash_attn(
    const unsigned short* __restrict__ Qg, const unsigned short* __restrict__ Kg,
    const unsigned short* __restrict__ Vtg, const float* __restrict__ x,
    const float* __restrict__ gamma, const float* __restrict__ beta,
    const float* __restrict__ mmean, const float* __restrict__ mvar,
    float* __restrict__ out) {
  __shared__ unsigned short Kt[16384];       // 32 KB single buffer, wave-private quarters
  __shared__ unsigned short Pbuf[2][8192];   // 2 x 16 KB (64 q x 128 key)

  const int b  = blockIdx.x & 7;
  const int qt = blockIdx.x >> 3;          // 0..63
  const int t = threadIdx.x;
  const int lane = t & 63;
  const int w = t >> 6;                    // 0..3
  const int l31 = lane & 31, hi = lane >> 5;
  const int lsw = l31 & 15;                // XOR-swizzle key (row&15)
  const int q0 = qt * 64;

  const unsigned short* Qb = Qg  + (size_t)b * 524288;
  const unsigned short* Kb = Kg  + (size_t)b * 524288;
  const unsigned short* Vb = Vtg + (size_t)b * 524288;

  // K[0] DMA FIRST (8 reqs, oldest vmcnt entries). Wave quarter = keys w*32..+32.
  {
    const unsigned short* src = Kb + (size_t)w * 4096 + lane * 8;
    unsigned short* dst = &Kt[w * 4096];
#pragma unroll
    for (int j = 0; j < 8; ++j) dma16(src + j * 512, dst + j * 512);
  }

  // Q B-frags: col q = q0 + nt*32 + l31; k(d) = ks*16 + hi*8 + [0..7]
  bf16x8 qf[2][8];
#pragma unroll
  for (int nt = 0; nt < 2; ++nt) {
    const unsigned short* qp = Qb + (size_t)(q0 + nt * 32 + l31) * 128 + hi * 8;
#pragma unroll
    for (int ks = 0; ks < 8; ++ks)
      qf[nt][ks] = __builtin_bit_cast(bf16x8, *(const uint4*)(qp + ks * 16));
  }

  f32x16 o[2];
#pragma unroll
  for (int nt = 0; nt < 2; ++nt)
#pragma unroll
    for (int r = 0; r < 16; ++r) o[nt][r] = 0.f;
  float lp[2] = {0.f, 0.f};
  bf16x8 vf[8];   // V[t] regs (own 32 d x 128 keys); consumed by PV[t] next iter

#pragma unroll 1
  for (int kt = 0; kt < 32; ++kt) {
    const int key0 = kt * 128;

    // K[kt] DMA landed: 8 oldest vmem entries (8 newer = qf tail / V[kt-1])
    asm volatile("s_waitcnt vmcnt(8)" ::: "memory");

    // S^T = K * Q^T: A = own 32 keys (LDS quarter, swizzled), B = qf.
    // 16 MFMA (2 nt x 8 ks), accumulate chains of 8.
    f32x16 sa[2];
#pragma unroll
    for (int nt = 0; nt < 2; ++nt)
#pragma unroll
      for (int r = 0; r < 16; ++r) sa[nt][r] = 0.f;
    {
      const unsigned short* kr = &Kt[(w * 32 + l31) * 128];
      bf16x8 kf[8];
#pragma unroll
      for (int ks = 0; ks < 8; ++ks)
        kf[ks] = __builtin_bit_cast(bf16x8,
            *(const uint4*)(kr + (((ks * 2 + hi) ^ lsw)) * 8));
#pragma unroll
      for (int ks = 0; ks < 8; ++ks)
#pragma unroll
        for (int nt = 0; nt < 2; ++nt)
          sa[nt] = __builtin_amdgcn_mfma_f32_32x32x16_bf16(kf[ks], qf[nt][ks], sa[nt], 0, 0, 0);
    }

    // softmax[kt] -> Pbuf[kt&1]. Lane's keys (C layout): local key =
    // g*8 + hi*4 + j (g = reg>>2, j = reg&3), global = w*32 + that.
    // Chunk (8 keys / 16B) = w*4 + g, swizzled pos = (w*4+g) ^ (q&15).
    {
      unsigned short* Ps = Pbuf[kt & 1];
#pragma unroll
      for (int nt = 0; nt < 2; ++nt) {
        unsigned short* Pq = Ps + (nt * 32 + l31) * 128 + hi * 4;
#pragma unroll
        for (int g = 0; g < 4; ++g) {
          float e0 = fexp2(sa[nt][g * 4 + 0]), e1 = fexp2(sa[nt][g * 4 + 1]);
          float e2 = fexp2(sa[nt][g * 4 + 2]), e3 = fexp2(sa[nt][g * 4 + 3]);
          lp[nt] += (e0 + e1) + (e2 + e3);
          *(uint2*)(Pq + (((w * 4 + g) ^ lsw)) * 8) =
              make_uint2(pack2t(e0, e1), pack2t(e2, e3));
        }
      }
    }

    // own kf reads retired -> safe to overwrite own quarter; DMA K[kt+1]
    asm volatile("s_waitcnt lgkmcnt(0)" ::: "memory");
    if (kt + 1 < 32) {
      const unsigned short* src = Kb + (size_t)(kt + 1) * 16384 + w * 4096 + lane * 8;
      unsigned short* dst = &Kt[w * 4096];
#pragma unroll
      for (int j = 0; j < 8; ++j) dma16(src + j * 512, dst + j * 512);
    }

    // PV[kt-1]: O^T += V^T[kt-1] * P^T[kt-1] (Pbuf[(kt-1)&1], vf regs).
    // B-frag: col q = l31, keys = ks*16 + hi*8 -> chunk ks*2+hi, swizzled.
    // vf wait compiler-counted (8 DMA newer -> vmcnt(8)), DMA stays live.
    if (kt > 0) {
      const unsigned short* Pp = Pbuf[(kt & 1) ^ 1];
#pragma unroll
      for (int nt = 0; nt < 2; ++nt) {
        const unsigned short* Pq = Pp + (size_t)(nt * 32 + l31) * 128;
        bf16x8 pf[8];
#pragma unroll
        for (int ks = 0; ks < 8; ++ks)
          pf[ks] = __builtin_bit_cast(bf16x8,
              *(const uint4*)(Pq + (((ks * 2 + hi) ^ lsw)) * 8));
#pragma unroll
        for (int ks = 0; ks < 8; ++ks)
          o[nt] = __builtin_amdgcn_mfma_f32_32x32x16_bf16(vf[ks], pf[ks], o[nt], 0, 0, 0);
      }
    }

    // V[kt] loads -> vf: A rows d = w*32 + l31; keys = ks*16 + hi*8 + [0..7]
    {
      const unsigned short* vp = Vb + (size_t)(w * 32 + l31) * 4096 + key0 + hi * 8;
#pragma unroll
      for (int ks = 0; ks < 8; ++ks)
        vf[ks] = __builtin_bit_cast(bf16x8, *(const uint4*)(vp + ks * 16));
    }

    // single barrier: P[kt] visible; all pf reads of Pbuf[(kt-1)&1] retired
    // (lgkm only -- V loads + K DMA stay in flight)
    asm volatile("s_waitcnt lgkmcnt(0)\n\ts_barrier" ::: "memory");
  }

  // epilogue: PV[31] (Pbuf[1], vf = V[31]; compiler waits the V loads)
  {
    const unsigned short* Pp = Pbuf[1];
#pragma unroll
    for (int nt = 0; nt < 2; ++nt) {
      const unsigned short* Pq = Pp + (size_t)(nt * 32 + l31) * 128;
      bf16x8 pf[8];
#pragma unroll
      for (int ks = 0; ks < 8; ++ks)
        pf[ks] = __builtin_bit_cast(bf16x8,
            *(const uint4*)(Pq + (((ks * 2 + hi) ^ lsw)) * 8));
#pragma unroll
      for (int ks = 0; ks < 8; ++ks)
        o[nt] = __builtin_amdgcn_mfma_f32_32x32x16_bf16(vf[ks], pf[ks], o[nt], 0, 0, 0);
    }
  }

  // l reduction: lane holds 16 of the wave's 32 keys; complementary half is
  // at lane^32 -> one shfl_xor(32). Cross-wave via Pbuf[0] floats (disjoint
  // from Pbuf[1] still read by other waves' epilogue PV).
  float* lred = (float*)Pbuf[0];
#pragma unroll
  for (int nt = 0; nt < 2; ++nt) lp[nt] += __shfl_xor(lp[nt], 32);
  if (hi == 0) {
#pragma unroll
    for (int nt = 0; nt < 2; ++nt) lred[w * 64 + nt * 32 + l31] = lp[nt];
  }
  __syncthreads();
  float rl[2];
#pragma unroll
  for (int nt = 0; nt < 2; ++nt) {
    int q = nt * 32 + l31;
    rl[nt] = 1.0f / ((lred[q] + lred[64 + q]) + (lred[128 + q] + lred[192 + q]));
  }

  // epilogue: lane's d rows = w*32 + g*8 + hi*4 + [0..3] (4 consecutive ->
  // float4), q = q0 + nt*32 + l31.
#pragma unroll
  for (int g = 0; g < 4; ++g) {
    int c0 = w * 32 + g * 8 + hi * 4;
    float4 gm = *(const float4*)(gamma + c0);
    float4 bt = *(const float4*)(beta + c0);
    float4 mm = *(const float4*)(mmean + c0);
    float4 mv = *(const float4*)(mvar + c0);
    float iv0 = gm.x * rsqrtf(mv.x + 1e-3f), iv1 = gm.y * rsqrtf(mv.y + 1e-3f);
    float iv2 = gm.z * rsqrtf(mv.z + 1e-3f), iv3 = gm.w * rsqrtf(mv.w + 1e-3f);
    float ad0 = bt.x - mm.x * iv0, ad1 = bt.y - mm.y * iv1;
    float ad2 = bt.z - mm.z * iv2, ad3 = bt.w - mm.w * iv3;
#pragma unroll
    for (int nt = 0; nt < 2; ++nt) {
      size_t gi = ((size_t)b * 4096 + q0 + nt * 32 + l31) * 128 + c0;
      float4 xr = *(const float4*)(x + gi);
      float4 ov;
      ov.x = (o[nt][g * 4 + 0] * rl[nt] + xr.x) * iv0 + ad0;
      ov.y = (o[nt][g * 4 + 1] * rl[nt] + xr.y) * iv1 + ad1;
      ov.z = (o[nt][g * 4 + 2] * rl[nt] + xr.z) * iv2 + ad2;
      ov.w = (o[nt][g * 4 + 3] * rl[nt] + xr.w) * iv3 + ad3;
      *(float4*)(out + gi) = ov;
    }
  }
}

// ---------------------------------------------------------------------------
extern "C" void kernel_launch(void* const* d_in, const int* in_sizes, int n_in,
                              void* d_out, int out_size, void* d_ws, size_t ws_size,
                              hipStream_t stream) {
  const float* x     = (const float*)d_in[0];
  const float* wq    = (const float*)d_in[1];
  const float* bq    = (const float*)d_in[2];
  const float* wk    = (const float*)d_in[3];
  const float* bk    = (const float*)d_in[4];
  const float* wv    = (const float*)d_in[5];
  const float* bv    = (const float*)d_in[6];
  const float* gamma = (const float*)d_in[7];
  const float* beta  = (const float*)d_in[8];
  const float* mmean = (const float*)d_in[9];
  const float* mvar  = (const float*)d_in[10];
  float* out = (float*)d_out;

  unsigned short* wt  = (unsigned short*)d_ws;
  unsigned short* Qg  = wt + 3 * 128 * 128;
  unsigned short* Kg  = Qg + 8 * 4096 * 128;     // pre-swizzled rows
  unsigned short* Vtg = Kg + 8 * 4096 * 128;

  prep_wt<<<dim3(3), dim3(256), 0, stream>>>(wq, wk, wv, wt);
  qkv_proj<<<dim3(512), dim3(256), 0, stream>>>(x, wt, bq, bk, bv, Qg, Kg, Vtg);
  flash_attn<<<dim3(512), dim3(256), 0, stream>>>(Qg, Kg, Vtg, x, gamma, beta,
                                                  mmean, mvar, out);
}

// Round 12
// 209.353 us; speedup vs baseline: 1.3047x; 1.0133x over previous
//
#include <hip/hip_runtime.h>

// Self-attention (B=8, N=4096, C=128) + residual + inference BatchNorm.
// R22: T15 (att[2]) applied to the R15 champion. R21 proved neither pipe's
// issue rate is the limiter (removed half the MFMA instrs + 30% VALU, time
// flat) -> the critical path is the WITHIN-WAVE dependency chain
// S -> softmax -> barrier -> PV. Break the S->softmax link: double-buffered
// sa (static names saA/saB, rule #20), softmax runs ONE TILE BEHIND so it is
// data-independent of the current S MFMAs and interleaves into their shadow.
// Per tile: vmcnt(8) -> S[t]->saCur || softmax(saPrev)->Pbuf[(t-1)&1] ->
// lgkm(0) -> DMA K[t+1] -> raw s_barrier (no drain attached) -> PV[t-1] ->
// V[t] loads. Buffer safety identical to R15 (write/read of Pbuf[(t-1)&1]
// straddle the same barrier; prior readers sealed by previous barrier).
// prep_wt / qkv_proj verbatim R15.
//
// ws: Wt 96KB | Qg 8M | Kg(swizzled) 8M | Vtg 8M  (~25.3 MB)

typedef __attribute__((ext_vector_type(8))) short bf16x8;
typedef __attribute__((ext_vector_type(4))) float f32x4;

__device__ __forceinline__ unsigned short f2bf(float f) {
  unsigned int u = __builtin_bit_cast(unsigned int, f);
  u += 0x7fffu + ((u >> 16) & 1u);   // RNE
  return (unsigned short)(u >> 16);
}
__device__ __forceinline__ unsigned int pack2(float a, float b) {
  return (unsigned int)f2bf(a) | ((unsigned int)f2bf(b) << 16);
}
// truncating pack via v_perm_b32: D = {b.hi16, a.hi16} in 1 VALU op
__device__ __forceinline__ unsigned int pack2t(float a, float b) {
  return __builtin_amdgcn_perm(__builtin_bit_cast(unsigned int, b),
                               __builtin_bit_cast(unsigned int, a),
                               0x07060302u);
}
// raw v_exp_f32 (args bounded: |s~| <~ 15, no guards needed)
__device__ __forceinline__ float fexp2(float x) {
  return __builtin_amdgcn_exp2f(x);
}

// async global->LDS DMA, 16B/lane: lds dest = uniform base + lane*16
__device__ __forceinline__ void dma16(const void* g, void* l) {
  __builtin_amdgcn_global_load_lds(
      (const __attribute__((address_space(1))) unsigned int*)g,
      (__attribute__((address_space(3))) unsigned int*)l, 16, 0, 0);
}

// 1/sqrt(128) * log2(e): softmax in exp2 domain; folded into Wq/bq.
#define SCALE_Q (0.08838834764831845f * 1.44269504088896340f)

// ---------------------------------------------------------------------------
// Kernel 1: W[k][n] fp32 -> Wt[n][k] bf16 (Wq pre-scaled). LDS-staged,
// coalesced loads (float4 linear) and stores (uint4, 16 lanes cover a row).
// ---------------------------------------------------------------------------
__global__ __launch_bounds__(256) void prep_wt(
    const float* __restrict__ wq, const float* __restrict__ wk,
    const float* __restrict__ wv, unsigned short* __restrict__ wt) {
  __shared__ float ws[128 * 129];   // padded: read bank spread
  const float* W = (blockIdx.x == 0) ? wq : (blockIdx.x == 1 ? wk : wv);
  const float sc = (blockIdx.x == 0) ? SCALE_Q : 1.0f;
  unsigned short* out = wt + blockIdx.x * 16384;
  const int t = threadIdx.x;

#pragma unroll
  for (int i = 0; i < 16; ++i) {
    int e = (i * 256 + t) * 4;          // linear float index, coalesced
    float4 v = *(const float4*)(W + e);
    int k = e >> 7, c = e & 127;
    float* d = ws + k * 129 + c;
    d[0] = v.x; d[1] = v.y; d[2] = v.z; d[3] = v.w;
  }
  __syncthreads();

  const int c = t & 15, n0 = t >> 4;   // 16 lanes cover one 256B output row
#pragma unroll
  for (int pass = 0; pass < 8; ++pass) {
    int n = pass * 16 + n0;
    const float* col = ws + n;
    unsigned int u0 = pack2(col[(c * 8 + 0) * 129] * sc, col[(c * 8 + 1) * 129] * sc);
    unsigned int u1 = pack2(col[(c * 8 + 2) * 129] * sc, col[(c * 8 + 3) * 129] * sc);
    unsigned int u2 = pack2(col[(c * 8 + 4) * 129] * sc, col[(c * 8 + 5) * 129] * sc);
    unsigned int u3 = pack2(col[(c * 8 + 6) * 129] * sc, col[(c * 8 + 7) * 129] * sc);
    *(uint4*)(out + n * 128 + c * 8) = make_uint4(u0, u1, u2, u3);
  }
}

// ---------------------------------------------------------------------------
// Kernel 2: fused QKV projection, grid(512). One x staging, three GEMMs with
// register-resident a-frags; obuf reused per-phase (barrier-separated).
// K stored pre-swizzled (chunk ^ row) with COALESCED stores (pos-major).
// ---------------------------------------------------------------------------
__global__ __launch_bounds__(256) void qkv_proj(
    const float* __restrict__ x, const unsigned short* __restrict__ wt,
    const float* __restrict__ bq, const float* __restrict__ bk, const float* __restrict__ bv,
    unsigned short* __restrict__ Qg, unsigned short* __restrict__ Kg,
    unsigned short* __restrict__ Vtg) {
  __shared__ unsigned short xs[64 * 128];    // swizzled bf16 x tile (16 KB)
  __shared__ unsigned short obuf[9216];      // bounce buffer (18 KB), reused x3
  const int t = threadIdx.x;
  const int rowblk = blockIdx.x * 64;

#pragma unroll
  for (int i = 0; i < 8; ++i) {
    int flat = t * 4 + i * 1024;
    int row = flat >> 7, col = flat & 127;
    float4 v = *(const float4*)(x + (size_t)(rowblk + row) * 128 + col);
    unsigned int u0 = pack2(v.x, v.y), u1 = pack2(v.z, v.w);
    int pos = (col >> 3) ^ (row & 15);
    *(uint2*)(xs + row * 128 + pos * 8 + (col & 7)) = make_uint2(u0, u1);
  }
  __syncthreads();

  const int lane = t & 63, wv_ = t >> 6;
  const int lm = lane & 15, quad = lane >> 4;

  bf16x8 a[4];
  {
    int row = wv_ * 16 + lm;
#pragma unroll
    for (int ks = 0; ks < 4; ++ks)
      a[ks] = __builtin_bit_cast(bf16x8,
          *(const uint4*)(xs + row * 128 + (((ks * 4 + quad) ^ lm) * 8)));
  }

  const int b   = rowblk >> 12;
  const int nb0 = rowblk & 4095;
  const f32x4 zero4 = {0.f, 0.f, 0.f, 0.f};

#pragma unroll
  for (int p = 0; p < 3; ++p) {
    const unsigned short* w = wt + p * 16384;
    const float* bias = (p == 0) ? bq : (p == 1 ? bk : bv);
    const float bsc = (p == 0) ? SCALE_Q : 1.0f;

    f32x4 acc[8];
#pragma unroll
    for (int ct = 0; ct < 8; ++ct) acc[ct] = zero4;

#pragma unroll
    for (int ct = 0; ct < 8; ++ct) {
      int n = ct * 16 + lm;
      const uint4* wp = (const uint4*)(w + n * 128 + quad * 8);
#pragma unroll
      for (int ks = 0; ks < 4; ++ks) {
        bf16x8 bfr = __builtin_bit_cast(bf16x8, wp[ks * 4]);
        acc[ct] = __builtin_amdgcn_mfma_f32_16x16x32_bf16(a[ks], bfr, acc[ct], 0, 0, 0);
      }
    }

    if (p < 2) {
      int rowb = wv_ * 16 + quad * 4;
#pragma unroll
      for (int ct = 0; ct < 8; ++ct) {
        int c = ct * 16 + lm;
        float bb = bias[c] * bsc;
#pragma unroll
        for (int r = 0; r < 4; ++r)
          obuf[(rowb + r) * 136 + c] = f2bf(acc[ct][r] + bb);
      }
      __syncthreads();
      unsigned short* og = (p == 0) ? Qg : Kg;
      int row = t >> 2;
#pragma unroll
      for (int j = 0; j < 4; ++j) {
        int pos = (t & 3) * 4 + j;                      // contiguous store pos
        int ch  = (p == 1) ? (pos ^ (row & 15)) : pos;  // LDS-side scatter
        uint4 vv = *(const uint4*)(obuf + row * 136 + ch * 8);
        *(uint4*)(og + (size_t)(rowblk + row) * 128 + pos * 8) = vv;
      }
      __syncthreads();   // obuf free for next phase
    } else {
      int key_base = wv_ * 16 + quad * 4;
#pragma unroll
      for (int ct = 0; ct < 8; ++ct) {
        int c = ct * 16 + lm;
        float bb = bias[c];
        unsigned int u0 = pack2(acc[ct][0] + bb, acc[ct][1] + bb);
        unsigned int u1 = pack2(acc[ct][2] + bb, acc[ct][3] + bb);
        *(uint2*)(obuf + c * 72 + key_base) = make_uint2(u0, u1);
      }
      __syncthreads();
      int d = t >> 1;
#pragma unroll
      for (int j = 0; j < 4; ++j) {
        int ch = (t & 1) * 4 + j;
        uint4 vv = *(const uint4*)(obuf + d * 72 + ch * 8);
        *(uint4*)(Vtg + (size_t)b * 524288 + (size_t)d * 4096 + nb0 + ch * 8) = vv;
      }
    }
  }
}

// ---------------------------------------------------------------------------
// Kernel 3: flash attention, sa double-buffered (softmax one tile behind).
// grid(512) = 8b (XCD-local K/V) x 64 q-tiles of 64 rows; 256 thr = 4 waves.
// ---------------------------------------------------------------------------

// One pipeline phase. SAC = sa state written by S[KT]; SAP = sa state of
// tile KT-1, consumed by softmax here (data-independent of S[KT]'s MFMAs).
#define PHASE(KT, SAC, SAP)                                                    \
  {                                                                            \
    const int kt_ = (KT);                                                      \
    /* K[kt_] DMA = 8 oldest vmem entries; V[kt_-1] (8 newer) stays live */    \
    asm volatile("s_waitcnt vmcnt(8)" ::: "memory");                           \
    _Pragma("unroll") for (int mt = 0; mt < 2; ++mt)                           \
      _Pragma("unroll") for (int nt = 0; nt < 4; ++nt) SAC[mt][nt] = zero4;    \
    _Pragma("unroll") for (int mt = 0; mt < 2; ++mt) {                         \
      const unsigned short* kr = &Kt[(w * 32 + mt * 16 + lm) * 128];           \
      bf16x8 kf[4];                                                            \
      _Pragma("unroll") for (int ks = 0; ks < 4; ++ks)                         \
        kf[ks] = __builtin_bit_cast(                                           \
            bf16x8, *(const uint4*)(kr + ((ks * 4 + quad) ^ lm) * 8));         \
      _Pragma("unroll") for (int ks = 0; ks < 4; ++ks)                         \
        _Pragma("unroll") for (int nt = 0; nt < 4; ++nt)                       \
          SAC[mt][nt] = __builtin_amdgcn_mfma_f32_16x16x32_bf16(               \
              kf[ks], qf[nt][ks], SAC[mt][nt], 0, 0, 0);                       \
    }                                                                          \
    /* softmax[kt_-1] (VALU) -- independent of S[kt_] above: interleaves */    \
    if (kt_ > 0) {                                                             \
      unsigned short* Ps = Pbuf[(kt_ - 1) & 1];                                \
      const int sub = (quad & 1) * 4;                                          \
      _Pragma("unroll") for (int mt = 0; mt < 2; ++mt) {                       \
        int c16 = w * 4 + mt * 2 + (quad >> 1);                                \
        int pos = c16 ^ lm;                                                    \
        _Pragma("unroll") for (int nt = 0; nt < 4; ++nt) {                     \
          float e0 = fexp2(SAP[mt][nt][0]), e1 = fexp2(SAP[mt][nt][1]);        \
          float e2 = fexp2(SAP[mt][nt][2]), e3 = fexp2(SAP[mt][nt][3]);        \
          lp[nt] += (e0 + e1) + (e2 + e3);                                     \
          *(uint2*)(Ps + (nt * 16 + lm) * 128 + pos * 8 + sub) =               \
              make_uint2(pack2t(e0, e1), pack2t(e2, e3));                      \
        }                                                                      \
      }                                                                        \
    }                                                                          \
    /* own kf reads + P writes drained -> K quarter free, P visible-ready */   \
    asm volatile("s_waitcnt lgkmcnt(0)" ::: "memory");                         \
    if (kt_ + 1 < 32) {                                                        \
      const unsigned short* src =                                              \
          Kb + (size_t)(kt_ + 1) * 16384 + w * 4096 + lane * 8;                \
      unsigned short* dst = &Kt[w * 4096];                                     \
      _Pragma("unroll") for (int j = 0; j < 8; ++j)                            \
        dma16(src + j * 512, dst + j * 512);                                   \
    }                                                                          \
    /* raw barrier: lgkm already 0; V loads + K DMA stay in flight */          \
    asm volatile("s_barrier" ::: "memory");                                    \
    /* PV[kt_-1]: P from Pbuf (all waves), V[kt_-1] from vf regs */            \
    if (kt_ > 0) {                                                             \
      const uint4* Pr = (const uint4*)Pbuf[(kt_ - 1) & 1];                     \
      _Pragma("unroll") for (int nt = 0; nt < 4; ++nt) {                       \
        bf16x8 pf[4];                                                          \
        _Pragma("unroll") for (int ks = 0; ks < 4; ++ks)                       \
          pf[ks] = __builtin_bit_cast(                                         \
              bf16x8, Pr[(nt * 16 + lm) * 16 + ((ks * 4 + quad) ^ lm)]);       \
        _Pragma("unroll") for (int ks = 0; ks < 4; ++ks)                       \
          _Pragma("unroll") for (int mt = 0; mt < 2; ++mt)                     \
            o[mt][nt] = __builtin_amdgcn_mfma_f32_16x16x32_bf16(               \
                vf[mt][ks], pf[ks], o[mt][nt], 0, 0, 0);                       \
      }                                                                        \
    }                                                                          \
    /* V[kt_] loads -> vf (consumed by PV[kt_] next phase) */                  \
    _Pragma("unroll") for (int mt = 0; mt < 2; ++mt) {                         \
      const uint4* vp = (const uint4*)(                                        \
          Vb + (size_t)(w * 32 + mt * 16 + lm) * 4096 + kt_ * 128 + quad * 8); \
      _Pragma("unroll") for (int ks = 0; ks < 4; ++ks)                         \
        vf[mt][ks] = __builtin_bit_cast(bf16x8, vp[ks * 4]);                   \
    }                                                                          \
  }

__global__ __launch_bounds__(256)
__attribute__((amdgpu_waves_per_eu(2, 2)))
void flash_attn(
    const unsigned short* __restrict__ Qg, const unsigned short* __restrict__ Kg,
    const unsigned short* __restrict__ Vtg, const float* __restrict__ x,
    const float* __restrict__ gamma, const float* __restrict__ beta,
    const float* __restrict__ mmean, const float* __restrict__ mvar,
    float* __restrict__ out) {
  __shared__ unsigned short Kt[16384];       // 32 KB single buffer, wave-private quarters
  __shared__ unsigned short Pbuf[2][8192];   // 2 x 16 KB (64 q x 128 key)

  const int b  = blockIdx.x & 7;
  const int qt = blockIdx.x >> 3;          // 0..63
  const int t = threadIdx.x;
  const int lane = t & 63;
  const int w = t >> 6;                    // 0..3
  const int lm = lane & 15, quad = lane >> 4;
  const int q0 = qt * 64;

  const unsigned short* Qb = Qg  + (size_t)b * 524288;
  const unsigned short* Kb = Kg  + (size_t)b * 524288;
  const unsigned short* Vb = Vtg + (size_t)b * 524288;

  // K[0] DMA FIRST (8 reqs, oldest vmcnt entries)
  {
    const unsigned short* src = Kb + (size_t)w * 4096 + lane * 8;
    unsigned short* dst = &Kt[w * 4096];
#pragma unroll
    for (int j = 0; j < 8; ++j) dma16(src + j * 512, dst + j * 512);
  }

  // Q as B-fragments (k=d, n=q), register-resident (pre-scaled)
  bf16x8 qf[4][4];
#pragma unroll
  for (int nt = 0; nt < 4; ++nt) {
    const uint4* qp = (const uint4*)(Qb + (size_t)(q0 + nt * 16 + lm) * 128 + quad * 8);
#pragma unroll
    for (int ks = 0; ks < 4; ++ks) qf[nt][ks] = __builtin_bit_cast(bf16x8, qp[ks * 4]);
  }

  const f32x4 zero4 = {0.f, 0.f, 0.f, 0.f};
  f32x4 o[2][4];
#pragma unroll
  for (int mt = 0; mt < 2; ++mt)
#pragma unroll
    for (int nt = 0; nt < 4; ++nt) o[mt][nt] = zero4;
  float lp[4] = {0.f, 0.f, 0.f, 0.f};
  bf16x8 vf[2][4];       // V[t] regs; consumed by PV[t] one phase later
  f32x4 saA[2][4], saB[2][4];   // sa double-buffer: STATIC names (rule #20)

  // 16 x 2 phases = tiles 0..31. Even tile -> saA, odd -> saB.
#pragma unroll 1
  for (int kt2 = 0; kt2 < 16; ++kt2) {
    PHASE(2 * kt2,     saA, saB)
    PHASE(2 * kt2 + 1, saB, saA)
  }

  // epilogue part 1: softmax[31] (saB) -> Pbuf[1]
  {
    unsigned short* Ps = Pbuf[1];
    const int sub = (quad & 1) * 4;
#pragma unroll
    for (int mt = 0; mt < 2; ++mt) {
      int c16 = w * 4 + mt * 2 + (quad >> 1);
      int pos = c16 ^ lm;
#pragma unroll
      for (int nt = 0; nt < 4; ++nt) {
        float e0 = fexp2(saB[mt][nt][0]), e1 = fexp2(saB[mt][nt][1]);
        float e2 = fexp2(saB[mt][nt][2]), e3 = fexp2(saB[mt][nt][3]);
        lp[nt] += (e0 + e1) + (e2 + e3);
        *(uint2*)(Ps + (nt * 16 + lm) * 128 + pos * 8 + sub) =
            make_uint2(pack2t(e0, e1), pack2t(e2, e3));
      }
    }
  }
  asm volatile("s_waitcnt lgkmcnt(0)\n\ts_barrier" ::: "memory");

  // epilogue part 2: PV[31] (Pbuf[1], vf = V[31]; compiler waits the V loads)
  {
    const uint4* Pr = (const uint4*)Pbuf[1];
#pragma unroll
    for (int nt = 0; nt < 4; ++nt) {
      bf16x8 pf[4];
#pragma unroll
      for (int ks = 0; ks < 4; ++ks)
        pf[ks] = __builtin_bit_cast(bf16x8, Pr[(nt * 16 + lm) * 16 + ((ks * 4 + quad) ^ lm)]);
#pragma unroll
      for (int ks = 0; ks < 4; ++ks)
#pragma unroll
        for (int mt = 0; mt < 2; ++mt)
          o[mt][nt] = __builtin_amdgcn_mfma_f32_16x16x32_bf16(vf[mt][ks], pf[ks], o[mt][nt], 0, 0, 0);
    }
  }

  // l reduction: quads (keys) in-wave, then across waves via Pbuf[0] floats
  // (disjoint from Pbuf[1] still being read by other waves' epilogue PV)
  float* lred = (float*)Pbuf[0];
#pragma unroll
  for (int nt = 0; nt < 4; ++nt) {
    lp[nt] += __shfl_xor(lp[nt], 16);
    lp[nt] += __shfl_xor(lp[nt], 32);
  }
  if (quad == 0) {
#pragma unroll
    for (int nt = 0; nt < 4; ++nt) lred[w * 64 + nt * 16 + lm] = lp[nt];
  }
  __syncthreads();
  float rl[4];
#pragma unroll
  for (int nt = 0; nt < 4; ++nt) {
    int q = nt * 16 + lm;
    rl[nt] = 1.0f / ((lred[q] + lred[64 + q]) + (lred[128 + q] + lred[192 + q]));
  }

  // epilogue: lane holds 4 consecutive d at fixed q -> float4 stores
#pragma unroll
  for (int mt = 0; mt < 2; ++mt) {
    int c0 = w * 32 + mt * 16 + quad * 4;
    float4 gm = *(const float4*)(gamma + c0);
    float4 bt = *(const float4*)(beta + c0);
    float4 mm = *(const float4*)(mmean + c0);
    float4 mv = *(const float4*)(mvar + c0);
    float iv0 = gm.x * rsqrtf(mv.x + 1e-3f), iv1 = gm.y * rsqrtf(mv.y + 1e-3f);
    float iv2 = gm.z * rsqrtf(mv.z + 1e-3f), iv3 = gm.w * rsqrtf(mv.w + 1e-3f);
    float ad0 = bt.x - mm.x * iv0, ad1 = bt.y - mm.y * iv1;
    float ad2 = bt.z - mm.z * iv2, ad3 = bt.w - mm.w * iv3;
#pragma unroll
    for (int nt = 0; nt < 4; ++nt) {
      size_t g = ((size_t)b * 4096 + q0 + nt * 16 + lm) * 128 + c0;
      float4 xr = *(const float4*)(x + g);
      float4 ov;
      ov.x = (o[mt][nt][0] * rl[nt] + xr.x) * iv0 + ad0;
      ov.y = (o[mt][nt][1] * rl[nt] + xr.y) * iv1 + ad1;
      ov.z = (o[mt][nt][2] * rl[nt] + xr.z) * iv2 + ad2;
      ov.w = (o[mt][nt][3] * rl[nt] + xr.w) * iv3 + ad3;
      *(float4*)(out + g) = ov;
    }
  }
}

// ---------------------------------------------------------------------------
extern "C" void kernel_launch(void* const* d_in, const int* in_sizes, int n_in,
                              void* d_out, int out_size, void* d_ws, size_t ws_size,
                              hipStream_t stream) {
  const float* x     = (const float*)d_in[0];
  const float* wq    = (const float*)d_in[1];
  const float* bq    = (const float*)d_in[2];
  const float* wk    = (const float*)d_in[3];
  const float* bk    = (const float*)d_in[4];
  const float* wv    = (const float*)d_in[5];
  const float* bv    = (const float*)d_in[6];
  const float* gamma = (const float*)d_in[7];
  const float* beta  = (const float*)d_in[8];
  const float* mmean = (const float*)d_in[9];
  const float* mvar  = (const float*)d_in[10];
  float* out = (float*)d_out;

  unsigned short* wt  = (unsigned short*)d_ws;
  unsigned short* Qg  = wt + 3 * 128 * 128;
  unsigned short* Kg  = Qg + 8 * 4096 * 128;     // pre-swizzled rows
  unsigned short* Vtg = Kg + 8 * 4096 * 128;

  prep_wt<<<dim3(3), dim3(256), 0, stream>>>(wq, wk, wv, wt);
  qkv_proj<<<dim3(512), dim3(256), 0, stream>>>(x, wt, bq, bk, bv, Qg, Kg, Vtg);
  flash_attn<<<dim3(512), dim3(256), 0, stream>>>(Qg, Kg, Vtg, x, gamma, beta,
                                                  mmean, mvar, out);
}

// Round 13
// 205.735 us; speedup vs baseline: 1.3276x; 1.0176x over previous
//
#include <hip/hip_runtime.h>

// Self-attention (B=8, N=4096, C=128) + residual + inference BatchNorm.
// R23: CONSOLIDATION -- exact revert to the R15 champion (206.5us total,
// flash 102.7us), the session's verified optimum.
// Session ledger: R14's 1-barrier PV-pipelined loop was the only win (-8.5us).
// Neutral: reorder (R16), 32x32 MFMA (R21), T15 sa-dbuf (R22), producer
// rewrite (R15, total-neutral). Regressions: every occupancy route --
// VGPR-squeeze via waves_per_eu/min-waves (R12/13/17: 64 VGPR kills Q/V
// prefetch, -65%), thin waves (R19), 8-wave split (R20: +40% FETCH).
// Structural conclusion: latency-bound at 2 fat waves/SIMD; grid x QBLK =
// 4096 closes the box (fat waves => QBLK=64 => grid 512 => 2 blocks/CU).
//
// flash: QBLK=64, KVBLK=128, 4 waves. Kt single 32KB (wave-private quarters,
// wave-local waitcnt only). Pbuf DOUBLE (2x16KB): PV pipelined 1 tile back ->
// ONE lgkm-only barrier/tile. Per tile: vmcnt(8)[K-DMA] -> S -> softmax ->
// Pbuf[t&1] -> lgkm, DMA K[t+1] -> PV[t-1] (Pbuf[(t-1)&1], vf regs) -> V[t]
// loads -> lgkm+barrier. waves_per_eu(2,2) = allocator must not squeeze.
//
// ws: Wt 96KB | Qg 8M | Kg(swizzled) 8M | Vtg 8M  (~25.3 MB)

typedef __attribute__((ext_vector_type(8))) short bf16x8;
typedef __attribute__((ext_vector_type(4))) float f32x4;

__device__ __forceinline__ unsigned short f2bf(float f) {
  unsigned int u = __builtin_bit_cast(unsigned int, f);
  u += 0x7fffu + ((u >> 16) & 1u);   // RNE
  return (unsigned short)(u >> 16);
}
__device__ __forceinline__ unsigned int pack2(float a, float b) {
  return (unsigned int)f2bf(a) | ((unsigned int)f2bf(b) << 16);
}
// truncating pack (P in [0,1]: bias negligible vs threshold; 3 VALU vs ~12)
__device__ __forceinline__ unsigned int pack2t(float a, float b) {
  return (__builtin_bit_cast(unsigned int, a) >> 16) |
         (__builtin_bit_cast(unsigned int, b) & 0xFFFF0000u);
}
// raw v_exp_f32 (args bounded: |s~| <~ 15, no guards needed)
__device__ __forceinline__ float fexp2(float x) {
  return __builtin_amdgcn_exp2f(x);
}

// async global->LDS DMA, 16B/lane: lds dest = uniform base + lane*16
__device__ __forceinline__ void dma16(const void* g, void* l) {
  __builtin_amdgcn_global_load_lds(
      (const __attribute__((address_space(1))) unsigned int*)g,
      (__attribute__((address_space(3))) unsigned int*)l, 16, 0, 0);
}

// 1/sqrt(128) * log2(e): softmax in exp2 domain; folded into Wq/bq.
#define SCALE_Q (0.08838834764831845f * 1.44269504088896340f)

// ---------------------------------------------------------------------------
// Kernel 1: W[k][n] fp32 -> Wt[n][k] bf16 (Wq pre-scaled). LDS-staged,
// coalesced loads (float4 linear) and stores (uint4, 16 lanes cover a row).
// ---------------------------------------------------------------------------
__global__ __launch_bounds__(256) void prep_wt(
    const float* __restrict__ wq, const float* __restrict__ wk,
    const float* __restrict__ wv, unsigned short* __restrict__ wt) {
  __shared__ float ws[128 * 129];   // padded: read bank spread
  const float* W = (blockIdx.x == 0) ? wq : (blockIdx.x == 1 ? wk : wv);
  const float sc = (blockIdx.x == 0) ? SCALE_Q : 1.0f;
  unsigned short* out = wt + blockIdx.x * 16384;
  const int t = threadIdx.x;

#pragma unroll
  for (int i = 0; i < 16; ++i) {
    int e = (i * 256 + t) * 4;          // linear float index, coalesced
    float4 v = *(const float4*)(W + e);
    int k = e >> 7, c = e & 127;
    float* d = ws + k * 129 + c;
    d[0] = v.x; d[1] = v.y; d[2] = v.z; d[3] = v.w;
  }
  __syncthreads();

  const int c = t & 15, n0 = t >> 4;   // 16 lanes cover one 256B output row
#pragma unroll
  for (int pass = 0; pass < 8; ++pass) {
    int n = pass * 16 + n0;
    const float* col = ws + n;
    unsigned int u0 = pack2(col[(c * 8 + 0) * 129] * sc, col[(c * 8 + 1) * 129] * sc);
    unsigned int u1 = pack2(col[(c * 8 + 2) * 129] * sc, col[(c * 8 + 3) * 129] * sc);
    unsigned int u2 = pack2(col[(c * 8 + 4) * 129] * sc, col[(c * 8 + 5) * 129] * sc);
    unsigned int u3 = pack2(col[(c * 8 + 6) * 129] * sc, col[(c * 8 + 7) * 129] * sc);
    *(uint4*)(out + n * 128 + c * 8) = make_uint4(u0, u1, u2, u3);
  }
}

// ---------------------------------------------------------------------------
// Kernel 2: fused QKV projection, grid(512). One x staging, three GEMMs with
// register-resident a-frags; obuf reused per-phase (barrier-separated).
// K stored pre-swizzled (chunk ^ row) with COALESCED stores (pos-major).
// ---------------------------------------------------------------------------
__global__ __launch_bounds__(256) void qkv_proj(
    const float* __restrict__ x, const unsigned short* __restrict__ wt,
    const float* __restrict__ bq, const float* __restrict__ bk, const float* __restrict__ bv,
    unsigned short* __restrict__ Qg, unsigned short* __restrict__ Kg,
    unsigned short* __restrict__ Vtg) {
  __shared__ unsigned short xs[64 * 128];    // swizzled bf16 x tile (16 KB)
  __shared__ unsigned short obuf[9216];      // bounce buffer (18 KB), reused x3
  const int t = threadIdx.x;
  const int rowblk = blockIdx.x * 64;

#pragma unroll
  for (int i = 0; i < 8; ++i) {
    int flat = t * 4 + i * 1024;
    int row = flat >> 7, col = flat & 127;
    float4 v = *(const float4*)(x + (size_t)(rowblk + row) * 128 + col);
    unsigned int u0 = pack2(v.x, v.y), u1 = pack2(v.z, v.w);
    int pos = (col >> 3) ^ (row & 15);
    *(uint2*)(xs + row * 128 + pos * 8 + (col & 7)) = make_uint2(u0, u1);
  }
  __syncthreads();

  const int lane = t & 63, wv_ = t >> 6;
  const int lm = lane & 15, quad = lane >> 4;

  bf16x8 a[4];
  {
    int row = wv_ * 16 + lm;
#pragma unroll
    for (int ks = 0; ks < 4; ++ks)
      a[ks] = __builtin_bit_cast(bf16x8,
          *(const uint4*)(xs + row * 128 + (((ks * 4 + quad) ^ lm) * 8)));
  }

  const int b   = rowblk >> 12;
  const int nb0 = rowblk & 4095;
  const f32x4 zero4 = {0.f, 0.f, 0.f, 0.f};

#pragma unroll
  for (int p = 0; p < 3; ++p) {
    const unsigned short* w = wt + p * 16384;
    const float* bias = (p == 0) ? bq : (p == 1 ? bk : bv);
    const float bsc = (p == 0) ? SCALE_Q : 1.0f;

    f32x4 acc[8];
#pragma unroll
    for (int ct = 0; ct < 8; ++ct) acc[ct] = zero4;

#pragma unroll
    for (int ct = 0; ct < 8; ++ct) {
      int n = ct * 16 + lm;
      const uint4* wp = (const uint4*)(w + n * 128 + quad * 8);
#pragma unroll
      for (int ks = 0; ks < 4; ++ks) {
        bf16x8 bfr = __builtin_bit_cast(bf16x8, wp[ks * 4]);
        acc[ct] = __builtin_amdgcn_mfma_f32_16x16x32_bf16(a[ks], bfr, acc[ct], 0, 0, 0);
      }
    }

    if (p < 2) {
      int rowb = wv_ * 16 + quad * 4;
#pragma unroll
      for (int ct = 0; ct < 8; ++ct) {
        int c = ct * 16 + lm;
        float bb = bias[c] * bsc;
#pragma unroll
        for (int r = 0; r < 4; ++r)
          obuf[(rowb + r) * 136 + c] = f2bf(acc[ct][r] + bb);
      }
      __syncthreads();
      unsigned short* og = (p == 0) ? Qg : Kg;
      int row = t >> 2;
#pragma unroll
      for (int j = 0; j < 4; ++j) {
        int pos = (t & 3) * 4 + j;                      // contiguous store pos
        int ch  = (p == 1) ? (pos ^ (row & 15)) : pos;  // LDS-side scatter
        uint4 vv = *(const uint4*)(obuf + row * 136 + ch * 8);
        *(uint4*)(og + (size_t)(rowblk + row) * 128 + pos * 8) = vv;
      }
      __syncthreads();   // obuf free for next phase
    } else {
      int key_base = wv_ * 16 + quad * 4;
#pragma unroll
      for (int ct = 0; ct < 8; ++ct) {
        int c = ct * 16 + lm;
        float bb = bias[c];
        unsigned int u0 = pack2(acc[ct][0] + bb, acc[ct][1] + bb);
        unsigned int u1 = pack2(acc[ct][2] + bb, acc[ct][3] + bb);
        *(uint2*)(obuf + c * 72 + key_base) = make_uint2(u0, u1);
      }
      __syncthreads();
      int d = t >> 1;
#pragma unroll
      for (int j = 0; j < 4; ++j) {
        int ch = (t & 1) * 4 + j;
        uint4 vv = *(const uint4*)(obuf + d * 72 + ch * 8);
        *(uint4*)(Vtg + (size_t)b * 524288 + (size_t)d * 4096 + nb0 + ch * 8) = vv;
      }
    }
  }
}

// ---------------------------------------------------------------------------
// Kernel 3: flash attention, PV pipelined one tile back, 1 barrier/tile.
// (the verified champion: R14 structure, best measured 101.8-102.7us)
// grid(512) = 8b (XCD-local K/V) x 64 q-tiles of 64 rows; 256 thr = 4 waves.
// ---------------------------------------------------------------------------
__global__ __launch_bounds__(256)
__attribute__((amdgpu_waves_per_eu(2, 2)))
void flash_attn(
    const unsigned short* __restrict__ Qg, const unsigned short* __restrict__ Kg,
    const unsigned short* __restrict__ Vtg, const float* __restrict__ x,
    const float* __restrict__ gamma, const float* __restrict__ beta,
    const float* __restrict__ mmean, const float* __restrict__ mvar,
    float* __restrict__ out) {
  __shared__ unsigned short Kt[16384];       // 32 KB single buffer, wave-private quarters
  __shared__ unsigned short Pbuf[2][8192];   // 2 x 16 KB (64 q x 128 key)

  const int b  = blockIdx.x & 7;
  const int qt = blockIdx.x >> 3;          // 0..63
  const int t = threadIdx.x;
  const int lane = t & 63;
  const int w = t >> 6;                    // 0..3
  const int lm = lane & 15, quad = lane >> 4;
  const int q0 = qt * 64;

  const unsigned short* Qb = Qg  + (size_t)b * 524288;
  const unsigned short* Kb = Kg  + (size_t)b * 524288;
  const unsigned short* Vb = Vtg + (size_t)b * 524288;

  // K[0] DMA FIRST (oldest vmcnt entries -> loop-top vmcnt(8) drains exactly
  // these even with the 16 qf loads behind them).
  {
    const unsigned short* src = Kb + (size_t)w * 4096 + lane * 8;
    unsigned short* dst = &Kt[w * 4096];
#pragma unroll
    for (int j = 0; j < 8; ++j) dma16(src + j * 512, dst + j * 512);
  }

  // Q as B-fragments (k=d, n=q), register-resident (pre-scaled)
  bf16x8 qf[4][4];
#pragma unroll
  for (int nt = 0; nt < 4; ++nt) {
    const uint4* qp = (const uint4*)(Qb + (size_t)(q0 + nt * 16 + lm) * 128 + quad * 8);
#pragma unroll
    for (int ks = 0; ks < 4; ++ks) qf[nt][ks] = __builtin_bit_cast(bf16x8, qp[ks * 4]);
  }

  const f32x4 zero4 = {0.f, 0.f, 0.f, 0.f};
  f32x4 o[2][4];
#pragma unroll
  for (int mt = 0; mt < 2; ++mt)
#pragma unroll
    for (int nt = 0; nt < 4; ++nt) o[mt][nt] = zero4;
  float lp[4] = {0.f, 0.f, 0.f, 0.f};
  bf16x8 vf[2][4];   // V[t] regs; consumed by PV[t] in iteration t+1 (guarded at t=0)

#pragma unroll 1
  for (int kt = 0; kt < 32; ++kt) {
    const int key0 = kt * 128;

    // K[kt] DMA landed: DMA(8) are the 8 oldest vmem entries; the 8 newer
    // (qf tail at kt=0 / V[kt-1] later) may stay in flight.
    asm volatile("s_waitcnt vmcnt(8)" ::: "memory");

    // S^T = K * Q^T from LDS K (swizzled chunks, wave-private rows)
    f32x4 sa[2][4];
#pragma unroll
    for (int mt = 0; mt < 2; ++mt)
#pragma unroll
      for (int nt = 0; nt < 4; ++nt) sa[mt][nt] = zero4;
#pragma unroll
    for (int mt = 0; mt < 2; ++mt) {
      const unsigned short* kr = &Kt[(w * 32 + mt * 16 + lm) * 128];
      bf16x8 kf[4];
#pragma unroll
      for (int ks = 0; ks < 4; ++ks)
        kf[ks] = __builtin_bit_cast(bf16x8, *(const uint4*)(kr + ((ks * 4 + quad) ^ lm) * 8));
#pragma unroll
      for (int ks = 0; ks < 4; ++ks)
#pragma unroll
        for (int nt = 0; nt < 4; ++nt)
          sa[mt][nt] = __builtin_amdgcn_mfma_f32_16x16x32_bf16(kf[ks], qf[nt][ks], sa[mt][nt], 0, 0, 0);
    }

    // softmax[kt] -> Pbuf[kt&1] (buffer last read at PV[kt-2], barrier-separated)
    {
      unsigned short* Ps = Pbuf[kt & 1];
      const int sub = (quad & 1) * 4;
#pragma unroll
      for (int mt = 0; mt < 2; ++mt) {
        int c16 = w * 4 + mt * 2 + (quad >> 1);
        int pos = c16 ^ lm;
#pragma unroll
        for (int nt = 0; nt < 4; ++nt) {
          float e0 = fexp2(sa[mt][nt][0]), e1 = fexp2(sa[mt][nt][1]);
          float e2 = fexp2(sa[mt][nt][2]), e3 = fexp2(sa[mt][nt][3]);
          lp[nt] += (e0 + e1) + (e2 + e3);
          *(uint2*)(Ps + (nt * 16 + lm) * 128 + pos * 8 + sub) =
              make_uint2(pack2t(e0, e1), pack2t(e2, e3));
        }
      }
    }

    // own kf reads (and P writes) retired -> safe to overwrite own K quarter
    asm volatile("s_waitcnt lgkmcnt(0)" ::: "memory");
    if (kt + 1 < 32) {
      const unsigned short* src = Kb + (size_t)(kt + 1) * 16384 + w * 4096 + lane * 8;
      unsigned short* dst = &Kt[w * 4096];
#pragma unroll
      for (int j = 0; j < 8; ++j) dma16(src + j * 512, dst + j * 512);
    }

    // PV[kt-1]: O^T += V^T[kt-1] * P^T[kt-1] (Pbuf[(kt-1)&1], vf regs).
    // vf wait is compiler-counted (8 DMA newer -> vmcnt(8)), DMA stays live.
    if (kt > 0) {
      const uint4* Pr = (const uint4*)Pbuf[(kt & 1) ^ 1];
#pragma unroll
      for (int nt = 0; nt < 4; ++nt) {
        bf16x8 pf[4];
#pragma unroll
        for (int ks = 0; ks < 4; ++ks)
          pf[ks] = __builtin_bit_cast(bf16x8, Pr[(nt * 16 + lm) * 16 + ((ks * 4 + quad) ^ lm)]);
#pragma unroll
        for (int ks = 0; ks < 4; ++ks)
#pragma unroll
          for (int mt = 0; mt < 2; ++mt)
            o[mt][nt] = __builtin_amdgcn_mfma_f32_16x16x32_bf16(vf[mt][ks], pf[ks], o[mt][nt], 0, 0, 0);
      }
    }

    // V[kt] loads -> vf (consumed next iteration: window = softmax+barrier+S)
#pragma unroll
    for (int mt = 0; mt < 2; ++mt) {
      const uint4* vp = (const uint4*)(Vb + (size_t)(w * 32 + mt * 16 + lm) * 4096 + key0 + quad * 8);
#pragma unroll
      for (int ks = 0; ks < 4; ++ks) vf[mt][ks] = __builtin_bit_cast(bf16x8, vp[ks * 4]);
    }

    // single barrier: P[kt] visible to all; all waves' pf reads of
    // Pbuf[(kt-1)&1] retired (lgkm only -- V loads + K DMA stay in flight)
    asm volatile("s_waitcnt lgkmcnt(0)\n\ts_barrier" ::: "memory");
  }

  // epilogue: PV[31] (Pbuf[1], vf = V[31]; compiler waits the V loads)
  {
    const uint4* Pr = (const uint4*)Pbuf[1];
#pragma unroll
    for (int nt = 0; nt < 4; ++nt) {
      bf16x8 pf[4];
#pragma unroll
      for (int ks = 0; ks < 4; ++ks)
        pf[ks] = __builtin_bit_cast(bf16x8, Pr[(nt * 16 + lm) * 16 + ((ks * 4 + quad) ^ lm)]);
#pragma unroll
      for (int ks = 0; ks < 4; ++ks)
#pragma unroll
        for (int mt = 0; mt < 2; ++mt)
          o[mt][nt] = __builtin_amdgcn_mfma_f32_16x16x32_bf16(vf[mt][ks], pf[ks], o[mt][nt], 0, 0, 0);
    }
  }

  // l reduction: quads (keys) in-wave, then across waves via Pbuf[0] floats
  // (disjoint from Pbuf[1] still being read by other waves' epilogue PV)
  float* lred = (float*)Pbuf[0];
#pragma unroll
  for (int nt = 0; nt < 4; ++nt) {
    lp[nt] += __shfl_xor(lp[nt], 16);
    lp[nt] += __shfl_xor(lp[nt], 32);
  }
  if (quad == 0) {
#pragma unroll
    for (int nt = 0; nt < 4; ++nt) lred[w * 64 + nt * 16 + lm] = lp[nt];
  }
  __syncthreads();
  float rl[4];
#pragma unroll
  for (int nt = 0; nt < 4; ++nt) {
    int q = nt * 16 + lm;
    rl[nt] = 1.0f / ((lred[q] + lred[64 + q]) + (lred[128 + q] + lred[192 + q]));
  }

  // epilogue: lane holds 4 consecutive d at fixed q -> float4 stores
#pragma unroll
  for (int mt = 0; mt < 2; ++mt) {
    int c0 = w * 32 + mt * 16 + quad * 4;
    float4 gm = *(const float4*)(gamma + c0);
    float4 bt = *(const float4*)(beta + c0);
    float4 mm = *(const float4*)(mmean + c0);
    float4 mv = *(const float4*)(mvar + c0);
    float iv0 = gm.x * rsqrtf(mv.x + 1e-3f), iv1 = gm.y * rsqrtf(mv.y + 1e-3f);
    float iv2 = gm.z * rsqrtf(mv.z + 1e-3f), iv3 = gm.w * rsqrtf(mv.w + 1e-3f);
    float ad0 = bt.x - mm.x * iv0, ad1 = bt.y - mm.y * iv1;
    float ad2 = bt.z - mm.z * iv2, ad3 = bt.w - mm.w * iv3;
#pragma unroll
    for (int nt = 0; nt < 4; ++nt) {
      size_t g = ((size_t)b * 4096 + q0 + nt * 16 + lm) * 128 + c0;
      float4 xr = *(const float4*)(x + g);
      float4 ov;
      ov.x = (o[mt][nt][0] * rl[nt] + xr.x) * iv0 + ad0;
      ov.y = (o[mt][nt][1] * rl[nt] + xr.y) * iv1 + ad1;
      ov.z = (o[mt][nt][2] * rl[nt] + xr.z) * iv2 + ad2;
      ov.w = (o[mt][nt][3] * rl[nt] + xr.w) * iv3 + ad3;
      *(float4*)(out + g) = ov;
    }
  }
}

// ---------------------------------------------------------------------------
extern "C" void kernel_launch(void* const* d_in, const int* in_sizes, int n_in,
                              void* d_out, int out_size, void* d_ws, size_t ws_size,
                              hipStream_t stream) {
  const float* x     = (const float*)d_in[0];
  const float* wq    = (const float*)d_in[1];
  const float* bq    = (const float*)d_in[2];
  const float* wk    = (const float*)d_in[3];
  const float* bk    = (const float*)d_in[4];
  const float* wv    = (const float*)d_in[5];
  const float* bv    = (const float*)d_in[6];
  const float* gamma = (const float*)d_in[7];
  const float* beta  = (const float*)d_in[8];
  const float* mmean = (const float*)d_in[9];
  const float* mvar  = (const float*)d_in[10];
  float* out = (float*)d_out;

  unsigned short* wt  = (unsigned short*)d_ws;
  unsigned short* Qg  = wt + 3 * 128 * 128;
  unsigned short* Kg  = Qg + 8 * 4096 * 128;     // pre-swizzled rows
  unsigned short* Vtg = Kg + 8 * 4096 * 128;

  prep_wt<<<dim3(3), dim3(256), 0, stream>>>(wq, wk, wv, wt);
  qkv_proj<<<dim3(512), dim3(256), 0, stream>>>(x, wt, bq, bk, bv, Qg, Kg, Vtg);
  flash_attn<<<dim3(512), dim3(256), 0, stream>>>(Qg, Kg, Vtg, x, gamma, beta,
                                                  mmean, mvar, out);
}